// Round 20
// baseline (197.583 us; speedup 1.0000x reference)
//
#include <hip/hip_runtime.h>
#include <hip/hip_cooperative_groups.h>
#include <stdint.h>

#pragma clang fp contract(off)

namespace cg = cooperative_groups;

#define NB 4
#define NN 8192
#define NC 3
#define NG 12
#define MAXN 500
#define KEEP_CAP 512

typedef unsigned long long u64;
typedef uint32_t u32;
typedef uint16_t u16;

// ---------- ws layout (bytes) ----------
#define NSO   0u
#define NSKEY 393216u
#define NSB4  786432u
#define NSAR  2359296u
#define NVAL  2752512u
#define NALV  2764800u
#define NKKEY 2777088u
#define NKPOS 2801664u
#define NKCNT 2826240u
#define NFLG  2826304u
#define PMAT  3145728u    // u64 [12][32][2048] prefix matrix, TRANSPOSED (aliased as kk)
#define WS_NEED 9437184u

#define PR_CH   32
#define PR_ROWS 2048
#define PUNITS_PER_G 528

// ---------- old-path (fallback) ws layout ----------
#define WS_SORTED_ORIG 0
#define WS_ALIVE       393216
#define WS_KEPT_KEY    405504
#define WS_KEPT_POS    430080
#define WS_KEPT_CNT    454656
#define NMS_EPS 1.0000004f

__device__ __forceinline__ u32 sort_key(float s) {
  u32 b = __float_as_uint(s);
  u32 o = (b & 0x80000000u) ? ~b : (b | 0x80000000u);
  return ~o;
}

#define PHYS(i) ((i) + ((i) >> 3))
#define CEX(A, B, UP) \
  { if ((x[A] > x[B]) == (UP)) { u64 tt = x[A]; x[A] = x[B]; x[B] = tt; } }

// ===================== fused cooperative kernel =====================
__global__ __launch_bounds__(1024) void fused_kernel(
    const float* __restrict__ in, u64* __restrict__ kk, u32* __restrict__ so,
    u32* __restrict__ skey, float4* __restrict__ sb4, float* __restrict__ sar,
    u64* __restrict__ valid, u64* __restrict__ pmat, u64* __restrict__ alive,
    u32* __restrict__ kkey, u32* __restrict__ kpos, u32* __restrict__ kcnt,
    u32* __restrict__ flags, float* __restrict__ out)
{
  cg::grid_group grid = cg::this_grid();
  __shared__ __align__(16) unsigned char smemraw[81920];
  const int tid = threadIdx.x;
  const int blk = blockIdx.x;
  const int lane = tid & 63;

  // ---------- phase 1: per-2048-segment ascending bitonic sort ----------
  {
    u64* sk = (u64*)smemraw;            // 2304 u64 = 18 KiB
    const int g = blk >> 2, seg = blk & 3;
    const int b = g / NC, c = g % NC;
    const float* __restrict__ base = in + (size_t)b * NN * 11;
    const int gbase = seg << 11;

    for (int i = tid; i < 2048; i += 1024) {
      int p = gbase + i;
      float sc = base[p * 11 + 7 + c];
      float s = (sc > 0.1f) ? sc : -INFINITY;
      sk[PHYS(i)] = ((u64)sort_key(s) << 16) | (u32)p;
    }
    __syncthreads();
    if (tid < 256) {
      const int pb = 9 * tid;
      u64 x[8];
#pragma unroll
      for (int a = 0; a < 8; ++a) x[a] = sk[pb + a];
      const bool u8 = ((((tid << 3)) & 8) == 0);
      CEX(0, 1, true); CEX(2, 3, false); CEX(4, 5, true); CEX(6, 7, false);
      CEX(0, 2, true); CEX(1, 3, true); CEX(4, 6, false); CEX(5, 7, false);
      CEX(0, 1, true); CEX(2, 3, true); CEX(4, 5, false); CEX(6, 7, false);
      CEX(0, 4, u8); CEX(1, 5, u8); CEX(2, 6, u8); CEX(3, 7, u8);
      CEX(0, 2, u8); CEX(1, 3, u8); CEX(4, 6, u8); CEX(5, 7, u8);
      CEX(0, 1, u8); CEX(2, 3, u8); CEX(4, 5, u8); CEX(6, 7, u8);
#pragma unroll
      for (int a = 0; a < 8; ++a) sk[pb + a] = x[a];
    }
    __syncthreads();
    for (int k = 16; k <= 2048; k <<= 1) {
      for (int j = k >> 1; j >= 8; j >>= 1) {
        {
          int t = tid;
          int i = (t << 1) - (t & (j - 1));
          int q = i | j;
          int pi = PHYS(i), pq = PHYS(q);
          u64 ka = sk[pi], kb = sk[pq];
          bool up = ((i & k) == 0);
          if ((ka > kb) == up) { sk[pi] = kb; sk[pq] = ka; }
        }
        __syncthreads();
      }
      if (tid < 256) {
        const int lb = tid << 3;
        const bool up = ((lb & k) == 0);
        const int pb = 9 * tid;
        u64 x[8];
#pragma unroll
        for (int a = 0; a < 8; ++a) x[a] = sk[pb + a];
        CEX(0, 4, up); CEX(1, 5, up); CEX(2, 6, up); CEX(3, 7, up);
        CEX(0, 2, up); CEX(1, 3, up); CEX(4, 6, up); CEX(5, 7, up);
        CEX(0, 1, up); CEX(2, 3, up); CEX(4, 5, up); CEX(6, 7, up);
#pragma unroll
        for (int a = 0; a < 8; ++a) sk[pb + a] = x[a];
      }
      __syncthreads();
    }
    for (int i = tid; i < 2048; i += 1024)
      kk[(size_t)g * NN + gbase + i] = sk[PHYS(i)];
  }
  grid.sync();

  // ---------- phase 2: merge (blocks 0..11): exact global top-2048 ----------
  if (blk < NG) {
    const int g = blk;
    const int b = g / NC;
    u64* seg = (u64*)smemraw;            // 64 KiB
    u64* outk = (u64*)(smemraw + 65536); // 16 KiB
    const u64* __restrict__ ks = kk + (size_t)g * NN;

    for (int e = tid; e < NN; e += 1024) seg[e] = ks[e];
    __syncthreads();

    for (int e = tid; e < NN; e += 1024) {
      const int sg = e >> 11, idx = e & 2047;
      const u64 k = seg[e];
      int rank = idx;
#pragma unroll
      for (int os = 0; os < 4; ++os) {
        if (os == sg) continue;
        const u64* __restrict__ arr = seg + (os << 11);
        int pos = 0;
#pragma unroll
        for (int st = 1024; st > 0; st >>= 1) {
          int np = pos + st;
          if (np <= 2048 && arr[np - 1] < k) pos = np;
        }
        rank += pos;
      }
      if (rank < PR_ROWS) outk[rank] = k;
    }
    __syncthreads();

    const float* __restrict__ base = in + (size_t)b * NN * 11;
#pragma unroll
    for (int it = 0; it < PR_ROWS / 1024; ++it) {
      int i = it * 1024 + tid;
      u64 kv = outk[i];
      int orig = (int)(kv & 0xFFFFu);
      u32 key32 = (u32)(kv >> 16);
      so[(size_t)g * NN + i] = (u32)orig;
      skey[(size_t)g * NN + i] = key32;
      const float* r = base + orig * 11;
      float x = r[0], y = r[1], l = r[3], wd = r[4];
      float hx = l * 0.5f, hy = wd * 0.5f;
      float x1 = x - hx, y1 = y - hy, x2 = x + hx, y2 = y + hy;
      sb4[(size_t)g * NN + i] = make_float4(x1, y1, x2, y2);
      sar[(size_t)g * NN + i] = (x2 - x1) * (y2 - y1);
      u64 bal = __ballot(key32 != 0xFF800000u);
      if (lane == 0) valid[g * 128 + (i >> 6)] = bal;
    }
  }
  grid.sync();

  // ---------- phase 3: build prefix matrix (all 768 waves) ----------
  {
    const int wib = __builtin_amdgcn_readfirstlane((int)(tid >> 6));
    const double CMULT = 0.25 * (1.0 + 0x1p-24);
    for (int W = blk * 16 + wib; W < NG * PUNITS_PER_G; W += 48 * 16) {
      const int g = W / PUNITS_PER_G;
      int r = W - g * PUNITS_PER_G;
      int rb = 0, cum = 0;
      while (r >= cum + (PR_CH - rb)) { cum += PR_CH - rb; ++rb; }
      const int jw = rb + (r - cum);

      const int col = jw * 64 + lane;
      const float4 J = sb4[(size_t)g * NN + col];
      const float jar = sar[(size_t)g * NN + col];
      const float4* __restrict__ Ib = sb4 + (size_t)g * NN + rb * 64;
      const float* __restrict__ Ia = sar + (size_t)g * NN + rb * 64;

      u32 accLo = 0, accHi = 0;
      for (int rr = 0; rr < 64; ++rr) {
        const float4 I = Ib[rr];
        const float iar = Ia[rr];
        const bool sel = (lane == rr);
        float iw = fminf(I.z, J.z) - fmaxf(I.x, J.x);
        float ih = fminf(I.w, J.w) - fmaxf(I.y, J.y);
        iw = fmaxf(iw, 0.0f); ih = fmaxf(ih, 0.0f);
        float inter = iw * ih;
        float denom = ((iar + jar) - inter) + 1e-8f;
        u64 cand = __ballot((double)inter > CMULT * (double)denom);
        accLo = sel ? (u32)(cand & 0xffffffffu) : accLo;
        accHi = sel ? (u32)(cand >> 32) : accHi;
      }
      pmat[((size_t)(g * PR_CH + jw)) * PR_ROWS + rb * 64 + lane] =
          ((u64)accHi << 32) | accLo;
    }
  }
  grid.sync();

  // ---------- phase 4: prefix scan (blocks 0..11) ----------
  {
    __shared__ u64 remv[PR_CH];
    __shared__ u64 keepw[PR_CH];
    __shared__ u64 keepS;
    __shared__ u32 prefixL[PR_CH];
    __shared__ u32 cntS;
    __shared__ int stopS;
    if (blk < NG) {
      const int g = blk;
      const int wv = tid >> 6;
      const int wl = tid & 127, grp = tid >> 7;

      if (tid < PR_CH) { remv[tid] = ~valid[g * 128 + tid]; keepw[tid] = 0; }
      if (tid == 0) { cntS = 0; stopS = 0; }
      __syncthreads();

      const u64* __restrict__ pm = pmat + (size_t)g * PR_CH * PR_ROWS;
      u64 rwDiag = 0, rwDiagNext = 0;
      if (wv == 0) rwDiag = pm[lane];
      const u64 maskgt = (lane == 63) ? 0ull : (~0ull << (lane + 1));

      for (int cc = 0; cc < PR_CH; ++cc) {
        const int w = cc + 1 + wl;
        const bool act = (w < PR_CH);
        u64 rw[8];
        if (act) {
#pragma unroll
          for (int k = 0; k < 8; ++k)
            rw[k] = pm[(size_t)w * PR_ROWS + cc * 64 + grp * 8 + k];
        }
        if (wv == 0) {
          const u64 alive0 = ~remv[cc];
          u64 K = alive0;
          for (int it = 0; it < 64; ++it) {
            u64 contrib = ((K >> lane) & 1ull) ? (rwDiag & maskgt) : 0ull;
#pragma unroll
            for (int off = 32; off > 0; off >>= 1)
              contrib |= (u64)__shfl_xor((long long)contrib, off);
            u64 Knew = alive0 & ~contrib;
            if (Knew == K) break;
            K = Knew;
          }
          if (lane == 0) {
            keepw[cc] = K; keepS = K;
            cntS += (u32)__popcll(K);
            if (cntS >= KEEP_CAP) stopS = 1;
          }
          if (cc + 1 < PR_CH)
            rwDiagNext = pm[(size_t)(cc + 1) * PR_ROWS + (cc + 1) * 64 + lane];
        }
        __syncthreads();
        if (stopS) break;
        if (act) {
          const u32 kmg = (u32)((keepS >> (grp * 8)) & 0xffu);
          u64 acc = 0;
#pragma unroll
          for (int k = 0; k < 8; ++k)
            if ((kmg >> k) & 1u) acc |= rw[k];
          if (acc) atomicOr(&remv[w], acc);
        }
        if (wv == 0) rwDiag = rwDiagNext;
        __syncthreads();
      }
      __syncthreads();

      if (tid == 0) {
        u32 acc = 0;
        for (int i = 0; i < PR_CH; ++i) { prefixL[i] = acc; acc += (u32)__popcll(keepw[i]); }
        cntS = acc;
        u32 ok = (acc >= KEEP_CAP) ? 1u : 0u;
        flags[g] = ok;
        if (ok) kcnt[g] = KEEP_CAP;
      }
      __syncthreads();
      if (cntS >= KEEP_CAP) {
        for (int p = tid; p < PR_ROWS; p += 1024) {
          int wd = p >> 6;
          u64 kw = keepw[wd];
          if ((kw >> (p & 63)) & 1ull) {
            u32 rank = prefixL[wd] + (u32)__popcll(kw & ((1ull << (p & 63)) - 1ull));
            if (rank < KEEP_CAP) {
              kkey[g * KEEP_CAP + rank] = skey[g * NN + p];
              kpos[g * KEEP_CAP + rank] = (u32)p;
            }
          }
        }
      }
    }
  }
  grid.sync();

  // ---------- phase 5: gated monolithic NMS (blocks 0..11, ~never runs) ----
  {
    __shared__ float4 keeperBuf[2][64];
    __shared__ int nkBuf[2];
    __shared__ u64 aliveArr[128];
    __shared__ u32 prefix[128];
    if (blk < NG && flags[blk] == 0u) {
      const int g = blk;
      const int b = g / NC, c = g % NC;
      const float* __restrict__ base = in + (size_t)b * NN * 11;
      u32* keys = (u32*)smemraw;                 // 32 KiB
      u16* sidx = (u16*)(smemraw + 32768);       // 16 KiB
      const int w = tid >> 6;

      for (int p = tid; p < NN; p += 1024) {
        float sc = base[p * 11 + 7 + c];
        float s = (sc > 0.1f) ? sc : -INFINITY;
        keys[p] = sort_key(s);
        sidx[p] = (u16)p;
      }
      __syncthreads();
      for (int k = 2; k <= NN; k <<= 1) {
        for (int j = k >> 1; j > 0; j >>= 1) {
          for (int t = tid; t < NN / 2; t += 1024) {
            int i = (t << 1) - (t & (j - 1));
            int q = i | j;
            u32 ka = keys[i], kb = keys[q];
            u16 ia = sidx[i], ib = sidx[q];
            bool gt = (ka > kb) || (ka == kb && ia > ib);
            bool up = ((i & k) == 0);
            if (gt == up) { keys[i] = kb; keys[q] = ka; sidx[i] = ib; sidx[q] = ia; }
          }
          __syncthreads();
        }
      }
      float bx1[8], by1[8], bx2[8], by2[8], barea[8];
      u64 alv[8];
#pragma unroll
      for (int k = 0; k < 8; ++k) {
        int p = k * 1024 + tid;
        u32 key = keys[p];
        int orig = sidx[p];
        so[(size_t)g * NN + p] = (u32)orig;
        const float* r = base + orig * 11;
        float x = r[0], y = r[1], l = r[3], wd = r[4];
        float hx = l * 0.5f, hy = wd * 0.5f;
        bx1[k] = x - hx; by1[k] = y - hy; bx2[k] = x + hx; by2[k] = y + hy;
        barea[k] = (bx2[k] - bx1[k]) * (by2[k] - by1[k]);
        alv[k] = __ballot(key != 0xFF800000u);
      }
      for (int cc = 0; cc < 128; ++cc) {
        __syncthreads();
        int nk_prev = (cc > 0) ? nkBuf[(cc - 1) & 1] : 0;
        if (nk_prev > 0) {
          const int par = (cc - 1) & 1;
          for (int j = 0; j < nk_prev; ++j) {
            float4 K = keeperBuf[par][j];
            float ka = (K.z - K.x) * (K.w - K.y);
#pragma unroll
            for (int k = 0; k < 8; ++k) {
              if ((k * 16 + w) < cc) continue;
              if (alv[k] == 0ull) continue;
              float iw = fminf(bx2[k], K.z) - fmaxf(bx1[k], K.x);
              float ih = fminf(by2[k], K.w) - fmaxf(by1[k], K.y);
              iw = fmaxf(iw, 0.0f); ih = fmaxf(ih, 0.0f);
              float inter = iw * ih;
              float denom = (barea[k] + ka) - inter + 1e-8f;
              float t = 0.25f * denom;
              u64 sup = __ballot(inter > t);
              u64 wnd = __ballot(inter > t && inter <= t * NMS_EPS);
              if (wnd) {
                bool bb = inter > t;
                if (bb && inter <= t * NMS_EPS) bb = (inter / denom) > 0.25f;
                sup = __ballot(bb);
              }
              alv[k] &= ~sup;
            }
          }
        }
        if (w == (cc & 15)) {
          float mx1 = 0.f, my1 = 0.f, mx2 = 0.f, my2 = 0.f, ma = 0.f;
          u64 m = 0ull;
#pragma unroll
          for (int k = 0; k < 8; ++k) if (k == (cc >> 4)) {
            mx1 = bx1[k]; my1 = by1[k]; mx2 = bx2[k]; my2 = by2[k]; ma = barea[k];
            m = alv[k];
          }
          u64 keepm = 0ull;
          int nk = 0;
          while (m) {
            int bp = __ffsll(m) - 1;
            keepm |= 1ull << bp;
            m &= ~(1ull << bp);
            float kx1 = __shfl(mx1, bp), ky1 = __shfl(my1, bp);
            float kx2 = __shfl(mx2, bp), ky2 = __shfl(my2, bp);
            float ka = (kx2 - kx1) * (ky2 - ky1);
            float iw = fminf(mx2, kx2) - fmaxf(mx1, kx1);
            float ih = fminf(my2, ky2) - fmaxf(my1, ky1);
            iw = fmaxf(iw, 0.0f); ih = fmaxf(ih, 0.0f);
            float inter = iw * ih;
            float denom = (ma + ka) - inter + 1e-8f;
            float t = 0.25f * denom;
            u64 sup = __ballot(inter > t);
            u64 wnd = __ballot(inter > t && inter <= t * NMS_EPS);
            if (wnd) {
              bool bb = inter > t;
              if (bb && inter <= t * NMS_EPS) bb = (inter / denom) > 0.25f;
              sup = __ballot(bb);
            }
            m &= ~sup;
            if (lane == bp) keeperBuf[cc & 1][nk] = make_float4(mx1, my1, mx2, my2);
            nk++;
          }
#pragma unroll
          for (int k = 0; k < 8; ++k) if (k == (cc >> 4)) alv[k] = keepm;
          if (lane == 0) nkBuf[cc & 1] = nk;
        }
      }
      __syncthreads();
      if (lane == 0) {
#pragma unroll
        for (int k = 0; k < 8; ++k) aliveArr[k * 16 + w] = alv[k];
      }
      __syncthreads();
      if (tid == 0) {
        u32 acc = 0;
        for (int i = 0; i < 128; ++i) { prefix[i] = acc; acc += (u32)__popcll(aliveArr[i]); }
        kcnt[g] = acc;
      }
      __syncthreads();
      for (int i = tid; i < 128; i += 1024) alive[g * 128 + i] = aliveArr[i];
#pragma unroll
      for (int k = 0; k < 8; ++k) {
        int word = k * 16 + w;
        u64 a = alv[k];
        if ((a >> lane) & 1ull) {
          u32 rank = prefix[word] + (u32)__popcll(a & ((1ull << lane) - 1ull));
          if (rank < KEEP_CAP) {
            int p = k * 1024 + tid;
            kkey[g * KEEP_CAP + rank] = keys[p];
            kpos[g * KEEP_CAP + rank] = (u32)p;
          }
        }
      }
    }
  }
  grid.sync();

  // ---------- phase 6: top-k via 3-way sorted merge (blocks 0..3) ----------
  {
    __shared__ int sT[3], sL[3];
    if (blk < NB) {
      const int b = blk;
      u64* arr = (u64*)smemraw;          // [3][512] = 12 KiB
      if (tid < 3) {
        int K = (int)kcnt[b * 3 + tid];
        sT[tid] = K;
        sL[tid] = min(K, KEEP_CAP);
      }
      __syncthreads();
      const int navail = sL[0] + sL[1] + sL[2];
      const int Ttot = sT[0] + sT[1] + sT[2];

      for (int s = tid; s < NC * KEEP_CAP; s += 1024) {
        int c = s >> 9, i = s & 511;
        u64 key = ~0ull;
        if (i < sL[c]) {
          int g = b * 3 + c;
          u64 k32 = kkey[g * KEEP_CAP + i];
          u32 pos = kpos[g * KEEP_CAP + i];
          key = (k32 << 15) | (u32)(c * NN + pos);
        }
        arr[c * KEEP_CAP + i] = key;
      }
      __syncthreads();

      for (int s = tid; s < NC * KEEP_CAP; s += 1024) {
        int c = s >> 9, i = s & 511;
        if (i >= sL[c]) continue;
        u64 k = arr[c * KEEP_CAP + i];
        int rank = i;
#pragma unroll
        for (int oc = 0; oc < NC; ++oc) {
          if (oc == c) continue;
          int lo = 0, hi = sL[oc];
          while (lo < hi) { int mid = (lo + hi) >> 1; if (arr[oc * KEEP_CAP + mid] < k) lo = mid + 1; else hi = mid; }
          rank += lo;
        }
        if (rank < MAXN) {
          u32 flat = (u32)(k & 32767u);
          int cc = (int)(flat >> 13), pos = (int)(flat & 8191);
          u32 k32 = (u32)(k >> 15);
          u32 o = ~k32;
          u32 bits = (o & 0x80000000u) ? (o ^ 0x80000000u) : ~o;
          float sval = __uint_as_float(bits);
          u32 orig = so[(size_t)(b * 3 + cc) * NN + pos];
          const float* row = in + ((size_t)b * NN + orig) * 11;
          const float PI_F = 3.14159265358979323846f;
          float theta = row[6];
          float v = theta / PI_F;
          float fl = floorf(v + 1.0f);
          float lp = theta - fl * PI_F;
          float ang = lp + (1.0f - row[10]) * PI_F;
          float* ob = out + ((size_t)b * MAXN + rank) * 7;
          ob[0] = row[0]; ob[1] = row[1]; ob[2] = row[2];
          ob[3] = row[3]; ob[4] = row[4]; ob[5] = row[5]; ob[6] = ang;
          out[NB * MAXN * 7 + b * MAXN + rank] = (float)cc;
          out[NB * MAXN * 7 + NB * MAXN + b * MAXN + rank] = sval;
        }
      }

      for (int r = navail + tid; r < MAXN; r += 1024) {
        int need = r - Ttot;
        int fflat = 0;
        for (int wd = 0; wd < 384; ++wd) {
          u64 a = alive[b * 384 + wd];
          int z = 64 - __popcll(a);
          if (need < z) {
            u64 na = ~a;
            for (int it = 0; it < need; ++it) na &= na - 1ull;
            fflat = wd * 64 + (__ffsll(na) - 1);
            break;
          }
          need -= z;
        }
        int c = fflat >> 13, pos = fflat & 8191;
        u32 orig = so[(size_t)(b * 3 + c) * NN + pos];
        const float* row = in + ((size_t)b * NN + orig) * 11;
        const float PI_F = 3.14159265358979323846f;
        float theta = row[6];
        float v = theta / PI_F;
        float fl = floorf(v + 1.0f);
        float lp = theta - fl * PI_F;
        float ang = lp + (1.0f - row[10]) * PI_F;
        float* ob = out + ((size_t)b * MAXN + r) * 7;
        ob[0] = row[0]; ob[1] = row[1]; ob[2] = row[2];
        ob[3] = row[3]; ob[4] = row[4]; ob[5] = row[5]; ob[6] = ang;
        out[NB * MAXN * 7 + b * MAXN + r] = (float)c;
        out[NB * MAXN * 7 + NB * MAXN + b * MAXN + r] = -INFINITY;
      }
    }
  }
}

// ================= standalone fallback (small ws): r2 nms + topk ==========
__global__ __launch_bounds__(1024) void nms_kernel(
    const float* __restrict__ in, u32* __restrict__ sorted_orig,
    u64* __restrict__ alive_out, u32* __restrict__ kept_key,
    u32* __restrict__ kept_pos, u32* __restrict__ kept_cnt)
{
  const int g = blockIdx.x;
  const int b = g / NC, c = g % NC;
  const float* __restrict__ base = in + (size_t)b * NN * 11;
  __shared__ u32 keys[NN];
  __shared__ u16 sidx[NN];
  __shared__ float4 keeperBuf[2][64];
  __shared__ int nkBuf[2];
  __shared__ u64 aliveArr[128];
  __shared__ u32 prefix[128];
  const int tid = threadIdx.x;
  const int w = tid >> 6, lane = tid & 63;

  for (int p = tid; p < NN; p += 1024) {
    float sc = base[p * 11 + 7 + c];
    float s = (sc > 0.1f) ? sc : -INFINITY;
    keys[p] = sort_key(s);
    sidx[p] = (u16)p;
  }
  __syncthreads();
  for (int k = 2; k <= NN; k <<= 1) {
    for (int j = k >> 1; j > 0; j >>= 1) {
      for (int t = tid; t < NN / 2; t += 1024) {
        int i = (t << 1) - (t & (j - 1));
        int q = i | j;
        u32 ka = keys[i], kb = keys[q];
        u16 ia = sidx[i], ib = sidx[q];
        bool gt = (ka > kb) || (ka == kb && ia > ib);
        bool up = ((i & k) == 0);
        if (gt == up) { keys[i] = kb; keys[q] = ka; sidx[i] = ib; sidx[q] = ia; }
      }
      __syncthreads();
    }
  }
  float bx1[8], by1[8], bx2[8], by2[8], barea[8];
  u64 alive[8];
#pragma unroll
  for (int k = 0; k < 8; ++k) {
    int p = k * 1024 + tid;
    u32 key = keys[p];
    int orig = sidx[p];
    sorted_orig[g * NN + p] = (u32)orig;
    const float* r = base + orig * 11;
    float x = r[0], y = r[1], l = r[3], wd = r[4];
    float hx = l * 0.5f, hy = wd * 0.5f;
    bx1[k] = x - hx; by1[k] = y - hy; bx2[k] = x + hx; by2[k] = y + hy;
    barea[k] = (bx2[k] - bx1[k]) * (by2[k] - by1[k]);
    alive[k] = __ballot(key != 0xFF800000u);
  }
  for (int cc = 0; cc < 128; ++cc) {
    __syncthreads();
    int nk_prev = (cc > 0) ? nkBuf[(cc - 1) & 1] : 0;
    if (nk_prev > 0) {
      const int par = (cc - 1) & 1;
      for (int j = 0; j < nk_prev; ++j) {
        float4 K = keeperBuf[par][j];
        float ka = (K.z - K.x) * (K.w - K.y);
#pragma unroll
        for (int k = 0; k < 8; ++k) {
          if ((k * 16 + w) < cc) continue;
          if (alive[k] == 0ull) continue;
          float iw = fminf(bx2[k], K.z) - fmaxf(bx1[k], K.x);
          float ih = fminf(by2[k], K.w) - fmaxf(by1[k], K.y);
          iw = fmaxf(iw, 0.0f); ih = fmaxf(ih, 0.0f);
          float inter = iw * ih;
          float denom = (barea[k] + ka) - inter + 1e-8f;
          float t = 0.25f * denom;
          u64 sup = __ballot(inter > t);
          u64 wnd = __ballot(inter > t && inter <= t * NMS_EPS);
          if (wnd) {
            bool bb = inter > t;
            if (bb && inter <= t * NMS_EPS) bb = (inter / denom) > 0.25f;
            sup = __ballot(bb);
          }
          alive[k] &= ~sup;
        }
      }
    }
    if (w == (cc & 15)) {
      float mx1 = 0.f, my1 = 0.f, mx2 = 0.f, my2 = 0.f, ma = 0.f;
      u64 m = 0ull;
#pragma unroll
      for (int k = 0; k < 8; ++k) if (k == (cc >> 4)) {
        mx1 = bx1[k]; my1 = by1[k]; mx2 = bx2[k]; my2 = by2[k]; ma = barea[k];
        m = alive[k];
      }
      u64 keepm = 0ull;
      int nk = 0;
      while (m) {
        int bp = __ffsll(m) - 1;
        keepm |= 1ull << bp;
        m &= ~(1ull << bp);
        float kx1 = __shfl(mx1, bp), ky1 = __shfl(my1, bp);
        float kx2 = __shfl(mx2, bp), ky2 = __shfl(my2, bp);
        float ka = (kx2 - kx1) * (ky2 - ky1);
        float iw = fminf(mx2, kx2) - fmaxf(mx1, kx1);
        float ih = fminf(my2, ky2) - fmaxf(my1, ky1);
        iw = fmaxf(iw, 0.0f); ih = fmaxf(ih, 0.0f);
        float inter = iw * ih;
        float denom = (ma + ka) - inter + 1e-8f;
        float t = 0.25f * denom;
        u64 sup = __ballot(inter > t);
        u64 wnd = __ballot(inter > t && inter <= t * NMS_EPS);
        if (wnd) {
          bool bb = inter > t;
          if (bb && inter <= t * NMS_EPS) bb = (inter / denom) > 0.25f;
          sup = __ballot(bb);
        }
        m &= ~sup;
        if (lane == bp) keeperBuf[cc & 1][nk] = make_float4(mx1, my1, mx2, my2);
        nk++;
      }
#pragma unroll
      for (int k = 0; k < 8; ++k) if (k == (cc >> 4)) alive[k] = keepm;
      if (lane == 0) nkBuf[cc & 1] = nk;
    }
  }
  __syncthreads();
  if (lane == 0) {
#pragma unroll
    for (int k = 0; k < 8; ++k) aliveArr[k * 16 + w] = alive[k];
  }
  __syncthreads();
  if (tid == 0) {
    u32 acc = 0;
    for (int i = 0; i < 128; ++i) { prefix[i] = acc; acc += (u32)__popcll(aliveArr[i]); }
    kept_cnt[g] = acc;
  }
  __syncthreads();
  for (int i = tid; i < 128; i += 1024) alive_out[g * 128 + i] = aliveArr[i];
#pragma unroll
  for (int k = 0; k < 8; ++k) {
    int word = k * 16 + w;
    u64 a = alive[k];
    if ((a >> lane) & 1ull) {
      u32 rank = prefix[word] + (u32)__popcll(a & ((1ull << lane) - 1ull));
      if (rank < KEEP_CAP) {
        int p = k * 1024 + tid;
        kept_key[g * KEEP_CAP + rank] = keys[p];
        kept_pos[g * KEEP_CAP + rank] = (u32)p;
      }
    }
  }
}

__global__ __launch_bounds__(512) void topk_kernel(
    const float* __restrict__ in, const u32* __restrict__ sorted_orig,
    const u64* __restrict__ alive_ws, const u32* __restrict__ kept_key,
    const u32* __restrict__ kept_pos, const u32* __restrict__ kept_cnt,
    float* __restrict__ out)
{
  const int b = blockIdx.x;
  const int tid = threadIdx.x;
  __shared__ u64 arr[NC][KEEP_CAP];
  __shared__ int sT[3], sL[3];
  if (tid < 3) {
    int K = (int)kept_cnt[b * 3 + tid];
    sT[tid] = K;
    sL[tid] = min(K, KEEP_CAP);
  }
  __syncthreads();
  const int navail = sL[0] + sL[1] + sL[2];
  const int Ttot = sT[0] + sT[1] + sT[2];

  for (int s = tid; s < NC * KEEP_CAP; s += 512) {
    int c = s >> 9, i = s & 511;
    u64 key = ~0ull;
    if (i < sL[c]) {
      int g = b * 3 + c;
      u64 k32 = kept_key[g * KEEP_CAP + i];
      u32 pos = kept_pos[g * KEEP_CAP + i];
      key = (k32 << 15) | (u32)(c * NN + pos);
    }
    arr[c][i] = key;
  }
  __syncthreads();

  for (int s = tid; s < NC * KEEP_CAP; s += 512) {
    int c = s >> 9, i = s & 511;
    if (i >= sL[c]) continue;
    u64 k = arr[c][i];
    int rank = i;
#pragma unroll
    for (int oc = 0; oc < NC; ++oc) {
      if (oc == c) continue;
      int lo = 0, hi = sL[oc];
      while (lo < hi) { int mid = (lo + hi) >> 1; if (arr[oc][mid] < k) lo = mid + 1; else hi = mid; }
      rank += lo;
    }
    if (rank < MAXN) {
      u32 flat = (u32)(k & 32767u);
      int cc = (int)(flat >> 13), pos = (int)(flat & 8191);
      u32 k32 = (u32)(k >> 15);
      u32 o = ~k32;
      u32 bits = (o & 0x80000000u) ? (o ^ 0x80000000u) : ~o;
      float sval = __uint_as_float(bits);
      u32 orig = sorted_orig[(b * 3 + cc) * NN + pos];
      const float* row = in + ((size_t)b * NN + orig) * 11;
      const float PI_F = 3.14159265358979323846f;
      float theta = row[6];
      float v = theta / PI_F;
      float fl = floorf(v + 1.0f);
      float lp = theta - fl * PI_F;
      float ang = lp + (1.0f - row[10]) * PI_F;
      float* ob = out + ((size_t)b * MAXN + rank) * 7;
      ob[0] = row[0]; ob[1] = row[1]; ob[2] = row[2];
      ob[3] = row[3]; ob[4] = row[4]; ob[5] = row[5]; ob[6] = ang;
      out[NB * MAXN * 7 + b * MAXN + rank] = (float)cc;
      out[NB * MAXN * 7 + NB * MAXN + b * MAXN + rank] = sval;
    }
  }

  for (int r = navail + tid; r < MAXN; r += 512) {
    int need = r - Ttot;
    int fflat = 0;
    for (int wd = 0; wd < 384; ++wd) {
      u64 a = alive_ws[b * 384 + wd];
      int z = 64 - __popcll(a);
      if (need < z) {
        u64 na = ~a;
        for (int it = 0; it < need; ++it) na &= na - 1ull;
        fflat = wd * 64 + (__ffsll(na) - 1);
        break;
      }
      need -= z;
    }
    int c = fflat >> 13, pos = fflat & 8191;
    u32 orig = sorted_orig[(b * 3 + c) * NN + pos];
    const float* row = in + ((size_t)b * NN + orig) * 11;
    const float PI_F = 3.14159265358979323846f;
    float theta = row[6];
    float v = theta / PI_F;
    float fl = floorf(v + 1.0f);
    float lp = theta - fl * PI_F;
    float ang = lp + (1.0f - row[10]) * PI_F;
    float* ob = out + ((size_t)b * MAXN + r) * 7;
    ob[0] = row[0]; ob[1] = row[1]; ob[2] = row[2];
    ob[3] = row[3]; ob[4] = row[4]; ob[5] = row[5]; ob[6] = ang;
    out[NB * MAXN * 7 + b * MAXN + r] = (float)c;
    out[NB * MAXN * 7 + NB * MAXN + b * MAXN + r] = -INFINITY;
  }
}

extern "C" void kernel_launch(void* const* d_in, const int* in_sizes, int n_in,
                              void* d_out, int out_size, void* d_ws, size_t ws_size,
                              hipStream_t stream) {
  const float* in = (const float*)d_in[0];
  float* out = (float*)d_out;
  char* ws = (char*)d_ws;

  if (ws_size >= (size_t)WS_NEED) {
    u32* so = (u32*)(ws + NSO);
    u32* skey = (u32*)(ws + NSKEY);
    float4* sb4 = (float4*)(ws + NSB4);
    float* sar = (float*)(ws + NSAR);
    u64* valid = (u64*)(ws + NVAL);
    u64* alive = (u64*)(ws + NALV);
    u32* kkey = (u32*)(ws + NKKEY);
    u32* kpos = (u32*)(ws + NKPOS);
    u32* kcnt = (u32*)(ws + NKCNT);
    u32* flags = (u32*)(ws + NFLG);
    u64* pmat = (u64*)(ws + PMAT);
    u64* kk = (u64*)(ws + PMAT);

    void* args[] = { (void*)&in, (void*)&kk, (void*)&so, (void*)&skey,
                     (void*)&sb4, (void*)&sar, (void*)&valid, (void*)&pmat,
                     (void*)&alive, (void*)&kkey, (void*)&kpos, (void*)&kcnt,
                     (void*)&flags, (void*)&out };
    hipLaunchCooperativeKernel((const void*)fused_kernel, dim3(48), dim3(1024),
                               args, 0, stream);
  } else {
    u32* sorted_orig = (u32*)(ws + WS_SORTED_ORIG);
    u64* alive = (u64*)(ws + WS_ALIVE);
    u32* kept_key = (u32*)(ws + WS_KEPT_KEY);
    u32* kept_pos = (u32*)(ws + WS_KEPT_POS);
    u32* kept_cnt = (u32*)(ws + WS_KEPT_CNT);
    nms_kernel<<<dim3(NG), dim3(1024), 0, stream>>>(
        in, sorted_orig, alive, kept_key, kept_pos, kept_cnt);
    topk_kernel<<<dim3(NB), dim3(512), 0, stream>>>(
        in, sorted_orig, alive, kept_key, kept_pos, kept_cnt, out);
  }
}

// Round 21
// 97.975 us; speedup vs baseline: 2.0167x; 2.0167x over previous
//
#include <hip/hip_runtime.h>
#include <stdint.h>

#pragma clang fp contract(off)

#define NB 4
#define NN 8192
#define NC 3
#define NG 12
#define MAXN 500
#define KEEP_CAP 512

typedef unsigned long long u64;
typedef uint32_t u32;
typedef uint16_t u16;

// ---------- ws layout (bytes) ----------
#define NSO   0u
#define NSKEY 393216u
#define NSB4  786432u
#define NSAR  2359296u
#define NVAL  2752512u
#define NALV  2764800u
#define NKKEY 2777088u
#define NKPOS 2801664u
#define NKCNT 2826240u
#define NFLG  2826304u
#define PMAT  3145728u    // u64 [12][32][2048] prefix matrix, TRANSPOSED (aliased as kk)
#define WS_NEED 9437184u

#define PR_CH   32
#define PR_ROWS 2048
#define PUNITS_PER_G 528
#define PB_TPB 256
#define PB_BLOCKS 1584

// ---------- old-path (fallback) ws layout ----------
#define WS_SORTED_ORIG 0
#define WS_ALIVE       393216
#define WS_KEPT_KEY    405504
#define WS_KEPT_POS    430080
#define WS_KEPT_CNT    454656
#define NMS_EPS 1.0000004f

__device__ __forceinline__ u32 sort_key(float s) {
  u32 b = __float_as_uint(s);
  u32 o = (b & 0x80000000u) ? ~b : (b | 0x80000000u);
  return ~o;   // ascending key == descending float; -inf -> 0xFF800000
}

#define PHYS(i) ((i) + ((i) >> 3))
#define CEX(A, B, UP) \
  { if ((x[A] > x[B]) == (UP)) { u64 tt = x[A]; x[A] = x[B]; x[B] = tt; } }

// ========== sort stage 1: per-2048-segment ASCENDING bitonic sort ==========
__global__ __launch_bounds__(256) void sortL_kernel(
    const float* __restrict__ in, u64* __restrict__ kk)
{
  const int g = blockIdx.x >> 2, seg = blockIdx.x & 3;
  const int b = g / NC, c = g % NC;
  const float* __restrict__ base = in + (size_t)b * NN * 11;
  __shared__ u64 sk[2304];             // PHYS(2047)+1, 18 KiB
  const int tid = threadIdx.x;
  const int gbase = seg << 11;

  for (int i = tid; i < 2048; i += 256) {
    int p = gbase + i;
    float sc = base[p * 11 + 7 + c];
    float s = (sc > 0.1f) ? sc : -INFINITY;
    sk[PHYS(i)] = ((u64)sort_key(s) << 16) | (u32)p;
  }
  __syncthreads();
  {
    const int pb = 9 * tid;
    u64 x[8];
#pragma unroll
    for (int a = 0; a < 8; ++a) x[a] = sk[pb + a];
    const bool u8 = ((((tid << 3)) & 8) == 0);   // LOCAL index direction
    CEX(0, 1, true); CEX(2, 3, false); CEX(4, 5, true); CEX(6, 7, false);
    CEX(0, 2, true); CEX(1, 3, true); CEX(4, 6, false); CEX(5, 7, false);
    CEX(0, 1, true); CEX(2, 3, true); CEX(4, 5, false); CEX(6, 7, false);
    CEX(0, 4, u8); CEX(1, 5, u8); CEX(2, 6, u8); CEX(3, 7, u8);
    CEX(0, 2, u8); CEX(1, 3, u8); CEX(4, 6, u8); CEX(5, 7, u8);
    CEX(0, 1, u8); CEX(2, 3, u8); CEX(4, 5, u8); CEX(6, 7, u8);
#pragma unroll
    for (int a = 0; a < 8; ++a) sk[pb + a] = x[a];
  }
  __syncthreads();
  for (int k = 16; k <= 2048; k <<= 1) {
    for (int j = k >> 1; j >= 8; j >>= 1) {
      for (int t = tid; t < 1024; t += 256) {
        int i = (t << 1) - (t & (j - 1));
        int q = i | j;
        int pi = PHYS(i), pq = PHYS(q);
        u64 ka = sk[pi], kb = sk[pq];
        bool up = ((i & k) == 0);                // LOCAL index direction
        if ((ka > kb) == up) { sk[pi] = kb; sk[pq] = ka; }
      }
      __syncthreads();
    }
    {
      const int lb = tid << 3;
      const bool up = ((lb & k) == 0);
      const int pb = 9 * tid;
      u64 x[8];
#pragma unroll
      for (int a = 0; a < 8; ++a) x[a] = sk[pb + a];
      CEX(0, 4, up); CEX(1, 5, up); CEX(2, 6, up); CEX(3, 7, up);
      CEX(0, 2, up); CEX(1, 3, up); CEX(4, 6, up); CEX(5, 7, up);
      CEX(0, 1, up); CEX(2, 3, up); CEX(4, 5, up); CEX(6, 7, up);
#pragma unroll
      for (int a = 0; a < 8; ++a) sk[pb + a] = x[a];
    }
    __syncthreads();
  }
  for (int i = tid; i < 2048; i += 256)
    kk[(size_t)g * NN + gbase + i] = sk[PHYS(i)];
}

// ========== merge: exact global top-2048; searches run in LDS ==============
__global__ __launch_bounds__(1024) void merge_kernel(
    const float* __restrict__ in, const u64* __restrict__ kk,
    u32* __restrict__ so, u32* __restrict__ skey, float4* __restrict__ sb4,
    float* __restrict__ sar, u64* __restrict__ valid)
{
  const int g = blockIdx.x;
  const int b = g / NC;
  const int tid = threadIdx.x;
  __shared__ u64 seg[NN];              // 64 KiB
  __shared__ u64 outk[PR_ROWS];        // 16 KiB
  const u64* __restrict__ ks = kk + (size_t)g * NN;

  for (int e = tid; e < NN; e += 1024) seg[e] = ks[e];
  __syncthreads();

  for (int e = tid; e < NN; e += 1024) {
    const int sg = e >> 11, idx = e & 2047;
    const u64 k = seg[e];
    int rank = idx;
#pragma unroll
    for (int os = 0; os < 4; ++os) {
      if (os == sg) continue;
      const u64* __restrict__ arr = seg + (os << 11);
      int pos = 0;
#pragma unroll
      for (int st = 1024; st > 0; st >>= 1) {
        int np = pos + st;
        if (np <= 2048 && arr[np - 1] < k) pos = np;
      }
      rank += pos;
    }
    if (rank < PR_ROWS) outk[rank] = k;
  }
  __syncthreads();

  const float* __restrict__ base = in + (size_t)b * NN * 11;
  const int lane = tid & 63;
#pragma unroll
  for (int it = 0; it < PR_ROWS / 1024; ++it) {
    int i = it * 1024 + tid;
    u64 kv = outk[i];
    int orig = (int)(kv & 0xFFFFu);
    u32 key32 = (u32)(kv >> 16);
    so[(size_t)g * NN + i] = (u32)orig;
    skey[(size_t)g * NN + i] = key32;
    const float* r = base + orig * 11;
    float x = r[0], y = r[1], l = r[3], wd = r[4];
    float hx = l * 0.5f, hy = wd * 0.5f;
    float x1 = x - hx, y1 = y - hy, x2 = x + hx, y2 = y + hy;
    sb4[(size_t)g * NN + i] = make_float4(x1, y1, x2, y2);
    sar[(size_t)g * NN + i] = (x2 - x1) * (y2 - y1);
    u64 bal = __ballot(key32 != 0xFF800000u);
    if (lane == 0) valid[g * 128 + (i >> 6)] = bal;
  }
}

// ================= prefix build: rows 0..2047 x words 0..31 (upper tri) ====
__global__ __launch_bounds__(PB_TPB) void build_prefix_kernel(
    const float4* __restrict__ sb4, const float* __restrict__ sar,
    u64* __restrict__ pmat)
{
  const int wib = __builtin_amdgcn_readfirstlane((int)(threadIdx.x >> 6));
  const int lane = threadIdx.x & 63;
  const int W = blockIdx.x * (PB_TPB / 64) + wib;
  if (W >= NG * PUNITS_PER_G) return;
  const int g = W / PUNITS_PER_G;
  int r = W - g * PUNITS_PER_G;
  int rb = 0, cum = 0;
  while (r >= cum + (PR_CH - rb)) { cum += PR_CH - rb; ++rb; }
  const int jw = rb + (r - cum);
  const double CMULT = 0.25 * (1.0 + 0x1p-24);   // exact in double

  const int col = jw * 64 + lane;
  const float4 J = sb4[(size_t)g * NN + col];
  const float jar = sar[(size_t)g * NN + col];
  const float4* __restrict__ Ib = sb4 + (size_t)g * NN + rb * 64;
  const float* __restrict__ Ia = sar + (size_t)g * NN + rb * 64;

  u32 accLo = 0, accHi = 0;
  for (int rr = 0; rr < 64; ++rr) {
    const float4 I = Ib[rr];            // uniform -> s_load
    const float iar = Ia[rr];
    const bool sel = (lane == rr);
    float iw = fminf(I.z, J.z) - fmaxf(I.x, J.x);
    float ih = fminf(I.w, J.w) - fmaxf(I.y, J.y);
    iw = fmaxf(iw, 0.0f); ih = fmaxf(ih, 0.0f);
    float inter = iw * ih;
    float denom = ((iar + jar) - inter) + 1e-8f;
    u64 cand = __ballot((double)inter > CMULT * (double)denom);
    accLo = sel ? (u32)(cand & 0xffffffffu) : accLo;
    accHi = sel ? (u32)(cand >> 32) : accHi;
  }
  pmat[((size_t)(g * PR_CH + jw)) * PR_ROWS + rb * 64 + lane] =
      ((u64)accHi << 32) | accLo;
}

// ======= prefix scan (fixpoint + early exit) + INLINE gated full NMS =======
__global__ __launch_bounds__(1024) void scan_nms_kernel(
    const u64* __restrict__ pmat, const u64* __restrict__ valid,
    const u32* __restrict__ skey, const float* __restrict__ in,
    u32* __restrict__ so, u64* __restrict__ alive_out,
    u32* __restrict__ kept_key, u32* __restrict__ kept_pos,
    u32* __restrict__ kept_cnt, u32* __restrict__ flags)
{
  const int g = blockIdx.x;
  const int tid = threadIdx.x;
  const int wv = tid >> 6, lane = tid & 63;
  const int wl = tid & 127, grp = tid >> 7;
  __shared__ u64 remv[PR_CH];
  __shared__ u64 keepw[PR_CH];
  __shared__ u64 keepS;
  __shared__ u32 prefixL[PR_CH];
  __shared__ u32 cntS;
  __shared__ int stopS;
  // NMS-path LDS (used only when flag==0)
  __shared__ u32 keys[NN];             // 32 KiB
  __shared__ u16 sidx[NN];             // 16 KiB
  __shared__ float4 keeperBuf[2][64];
  __shared__ int nkBuf[2];
  __shared__ u64 aliveArr[128];
  __shared__ u32 prefixN[128];

  if (tid < PR_CH) { remv[tid] = ~valid[g * 128 + tid]; keepw[tid] = 0; }
  if (tid == 0) { cntS = 0; stopS = 0; }
  __syncthreads();

  const u64* __restrict__ pm = pmat + (size_t)g * PR_CH * PR_ROWS;
  u64 rwDiag = 0, rwDiagNext = 0;
  if (wv == 0) rwDiag = pm[lane];
  const u64 maskgt = (lane == 63) ? 0ull : (~0ull << (lane + 1));

  for (int cc = 0; cc < PR_CH; ++cc) {
    const int w = cc + 1 + wl;
    const bool act = (w < PR_CH);
    u64 rw[8];
    if (act) {
#pragma unroll
      for (int k = 0; k < 8; ++k)
        rw[k] = pm[(size_t)w * PR_ROWS + cc * 64 + grp * 8 + k];
    }
    if (wv == 0) {
      const u64 alive0 = ~remv[cc];
      u64 K = alive0;
      for (int it = 0; it < 64; ++it) {
        u64 contrib = ((K >> lane) & 1ull) ? (rwDiag & maskgt) : 0ull;
#pragma unroll
        for (int off = 32; off > 0; off >>= 1)
          contrib |= (u64)__shfl_xor((long long)contrib, off);
        u64 Knew = alive0 & ~contrib;
        if (Knew == K) break;
        K = Knew;
      }
      if (lane == 0) {
        keepw[cc] = K; keepS = K;
        cntS += (u32)__popcll(K);
        if (cntS >= KEEP_CAP) stopS = 1;
      }
      if (cc + 1 < PR_CH)
        rwDiagNext = pm[(size_t)(cc + 1) * PR_ROWS + (cc + 1) * 64 + lane];
    }
    __syncthreads();
    if (stopS) break;
    if (act) {
      const u32 kmg = (u32)((keepS >> (grp * 8)) & 0xffu);
      u64 acc = 0;
#pragma unroll
      for (int k = 0; k < 8; ++k)
        if ((kmg >> k) & 1u) acc |= rw[k];
      if (acc) atomicOr(&remv[w], acc);
    }
    if (wv == 0) rwDiag = rwDiagNext;
    __syncthreads();
  }
  __syncthreads();

  if (tid == 0) {
    u32 acc = 0;
    for (int i = 0; i < PR_CH; ++i) { prefixL[i] = acc; acc += (u32)__popcll(keepw[i]); }
    cntS = acc;
    u32 ok = (acc >= KEEP_CAP) ? 1u : 0u;
    flags[g] = ok;
    if (ok) kept_cnt[g] = KEEP_CAP;
  }
  __syncthreads();
  if (cntS >= KEEP_CAP) {
    for (int p = tid; p < PR_ROWS; p += 1024) {
      int wd = p >> 6;
      u64 kw = keepw[wd];
      if ((kw >> (p & 63)) & 1ull) {
        u32 rank = prefixL[wd] + (u32)__popcll(kw & ((1ull << (p & 63)) - 1ull));
        if (rank < KEEP_CAP) {
          kept_key[g * KEEP_CAP + rank] = skey[g * NN + p];
          kept_pos[g * KEEP_CAP + rank] = (u32)p;
        }
      }
    }
    return;
  }

  // ---------- inline gated monolithic NMS (flag==0 only; ~never) ----------
  {
    const int b = g / NC, c = g % NC;
    const float* __restrict__ base = in + (size_t)b * NN * 11;
    const int w = tid >> 6;

    for (int p = tid; p < NN; p += 1024) {
      float sc = base[p * 11 + 7 + c];
      float s = (sc > 0.1f) ? sc : -INFINITY;
      keys[p] = sort_key(s);
      sidx[p] = (u16)p;
    }
    __syncthreads();
    for (int k = 2; k <= NN; k <<= 1) {
      for (int j = k >> 1; j > 0; j >>= 1) {
        for (int t = tid; t < NN / 2; t += 1024) {
          int i = (t << 1) - (t & (j - 1));
          int q = i | j;
          u32 ka = keys[i], kb = keys[q];
          u16 ia = sidx[i], ib = sidx[q];
          bool gt = (ka > kb) || (ka == kb && ia > ib);
          bool up = ((i & k) == 0);
          if (gt == up) { keys[i] = kb; keys[q] = ka; sidx[i] = ib; sidx[q] = ia; }
        }
        __syncthreads();
      }
    }
    float bx1[8], by1[8], bx2[8], by2[8], barea[8];
    u64 alv[8];
#pragma unroll
    for (int k = 0; k < 8; ++k) {
      int p = k * 1024 + tid;
      u32 key = keys[p];
      int orig = sidx[p];
      so[(size_t)g * NN + p] = (u32)orig;
      const float* r = base + orig * 11;
      float x = r[0], y = r[1], l = r[3], wd = r[4];
      float hx = l * 0.5f, hy = wd * 0.5f;
      bx1[k] = x - hx; by1[k] = y - hy; bx2[k] = x + hx; by2[k] = y + hy;
      barea[k] = (bx2[k] - bx1[k]) * (by2[k] - by1[k]);
      alv[k] = __ballot(key != 0xFF800000u);
    }
    for (int cc = 0; cc < 128; ++cc) {
      __syncthreads();
      int nk_prev = (cc > 0) ? nkBuf[(cc - 1) & 1] : 0;
      if (nk_prev > 0) {
        const int par = (cc - 1) & 1;
        for (int j = 0; j < nk_prev; ++j) {
          float4 K = keeperBuf[par][j];
          float ka = (K.z - K.x) * (K.w - K.y);
#pragma unroll
          for (int k = 0; k < 8; ++k) {
            if ((k * 16 + w) < cc) continue;
            if (alv[k] == 0ull) continue;
            float iw = fminf(bx2[k], K.z) - fmaxf(bx1[k], K.x);
            float ih = fminf(by2[k], K.w) - fmaxf(by1[k], K.y);
            iw = fmaxf(iw, 0.0f); ih = fmaxf(ih, 0.0f);
            float inter = iw * ih;
            float denom = (barea[k] + ka) - inter + 1e-8f;
            float t = 0.25f * denom;
            u64 sup = __ballot(inter > t);
            u64 wnd = __ballot(inter > t && inter <= t * NMS_EPS);
            if (wnd) {
              bool bb = inter > t;
              if (bb && inter <= t * NMS_EPS) bb = (inter / denom) > 0.25f;
              sup = __ballot(bb);
            }
            alv[k] &= ~sup;
          }
        }
      }
      if (w == (cc & 15)) {
        float mx1 = 0.f, my1 = 0.f, mx2 = 0.f, my2 = 0.f, ma = 0.f;
        u64 m = 0ull;
#pragma unroll
        for (int k = 0; k < 8; ++k) if (k == (cc >> 4)) {
          mx1 = bx1[k]; my1 = by1[k]; mx2 = bx2[k]; my2 = by2[k]; ma = barea[k];
          m = alv[k];
        }
        u64 keepm = 0ull;
        int nk = 0;
        while (m) {
          int bp = __ffsll(m) - 1;
          keepm |= 1ull << bp;
          m &= ~(1ull << bp);
          float kx1 = __shfl(mx1, bp), ky1 = __shfl(my1, bp);
          float kx2 = __shfl(mx2, bp), ky2 = __shfl(my2, bp);
          float ka = (kx2 - kx1) * (ky2 - ky1);
          float iw = fminf(mx2, kx2) - fmaxf(mx1, kx1);
          float ih = fminf(my2, ky2) - fmaxf(my1, ky1);
          iw = fmaxf(iw, 0.0f); ih = fmaxf(ih, 0.0f);
          float inter = iw * ih;
          float denom = (ma + ka) - inter + 1e-8f;
          float t = 0.25f * denom;
          u64 sup = __ballot(inter > t);
          u64 wnd = __ballot(inter > t && inter <= t * NMS_EPS);
          if (wnd) {
            bool bb = inter > t;
            if (bb && inter <= t * NMS_EPS) bb = (inter / denom) > 0.25f;
            sup = __ballot(bb);
          }
          m &= ~sup;
          if (lane == bp) keeperBuf[cc & 1][nk] = make_float4(mx1, my1, mx2, my2);
          nk++;
        }
#pragma unroll
        for (int k = 0; k < 8; ++k) if (k == (cc >> 4)) alv[k] = keepm;
        if (lane == 0) nkBuf[cc & 1] = nk;
      }
    }
    __syncthreads();
    if (lane == 0) {
#pragma unroll
      for (int k = 0; k < 8; ++k) aliveArr[k * 16 + w] = alv[k];
    }
    __syncthreads();
    if (tid == 0) {
      u32 acc = 0;
      for (int i = 0; i < 128; ++i) { prefixN[i] = acc; acc += (u32)__popcll(aliveArr[i]); }
      kept_cnt[g] = acc;
    }
    __syncthreads();
    for (int i = tid; i < 128; i += 1024) alive_out[g * 128 + i] = aliveArr[i];
#pragma unroll
    for (int k = 0; k < 8; ++k) {
      int word = k * 16 + w;
      u64 a = alv[k];
      if ((a >> lane) & 1ull) {
        u32 rank = prefixN[word] + (u32)__popcll(a & ((1ull << lane) - 1ull));
        if (rank < KEEP_CAP) {
          int p = k * 1024 + tid;
          kept_key[g * KEEP_CAP + rank] = keys[p];
          kept_pos[g * KEEP_CAP + rank] = (u32)p;
        }
      }
    }
  }
}

// ============ top-k via 3-way sorted-list merge (no bitonic) ===============
__global__ __launch_bounds__(512) void topk_kernel(
    const float* __restrict__ in, const u32* __restrict__ sorted_orig,
    const u64* __restrict__ alive_ws, const u32* __restrict__ kept_key,
    const u32* __restrict__ kept_pos, const u32* __restrict__ kept_cnt,
    float* __restrict__ out)
{
  const int b = blockIdx.x;
  const int tid = threadIdx.x;
  __shared__ u64 arr[NC][KEEP_CAP];
  __shared__ int sT[3], sL[3];
  if (tid < 3) {
    int K = (int)kept_cnt[b * 3 + tid];
    sT[tid] = K;
    sL[tid] = min(K, KEEP_CAP);
  }
  __syncthreads();
  const int navail = sL[0] + sL[1] + sL[2];
  const int Ttot = sT[0] + sT[1] + sT[2];

  for (int s = tid; s < NC * KEEP_CAP; s += 512) {
    int c = s >> 9, i = s & 511;
    u64 key = ~0ull;
    if (i < sL[c]) {
      int g = b * 3 + c;
      u64 k32 = kept_key[g * KEEP_CAP + i];
      u32 pos = kept_pos[g * KEEP_CAP + i];
      key = (k32 << 15) | (u32)(c * NN + pos);
    }
    arr[c][i] = key;
  }
  __syncthreads();

  for (int s = tid; s < NC * KEEP_CAP; s += 512) {
    int c = s >> 9, i = s & 511;
    if (i >= sL[c]) continue;
    u64 k = arr[c][i];
    int rank = i;
#pragma unroll
    for (int oc = 0; oc < NC; ++oc) {
      if (oc == c) continue;
      int lo = 0, hi = sL[oc];
      while (lo < hi) { int mid = (lo + hi) >> 1; if (arr[oc][mid] < k) lo = mid + 1; else hi = mid; }
      rank += lo;
    }
    if (rank < MAXN) {
      u32 flat = (u32)(k & 32767u);
      int cc = (int)(flat >> 13), pos = (int)(flat & 8191);
      u32 k32 = (u32)(k >> 15);
      u32 o = ~k32;
      u32 bits = (o & 0x80000000u) ? (o ^ 0x80000000u) : ~o;
      float sval = __uint_as_float(bits);
      u32 orig = sorted_orig[(b * 3 + cc) * NN + pos];
      const float* row = in + ((size_t)b * NN + orig) * 11;
      const float PI_F = 3.14159265358979323846f;
      float theta = row[6];
      float v = theta / PI_F;
      float fl = floorf(v + 1.0f);
      float lp = theta - fl * PI_F;
      float ang = lp + (1.0f - row[10]) * PI_F;
      float* ob = out + ((size_t)b * MAXN + rank) * 7;
      ob[0] = row[0]; ob[1] = row[1]; ob[2] = row[2];
      ob[3] = row[3]; ob[4] = row[4]; ob[5] = row[5]; ob[6] = ang;
      out[NB * MAXN * 7 + b * MAXN + rank] = (float)cc;
      out[NB * MAXN * 7 + NB * MAXN + b * MAXN + rank] = sval;
    }
  }

  for (int r = navail + tid; r < MAXN; r += 512) {
    int need = r - Ttot;
    int fflat = 0;
    for (int wd = 0; wd < 384; ++wd) {
      u64 a = alive_ws[b * 384 + wd];
      int z = 64 - __popcll(a);
      if (need < z) {
        u64 na = ~a;
        for (int it = 0; it < need; ++it) na &= na - 1ull;
        fflat = wd * 64 + (__ffsll(na) - 1);
        break;
      }
      need -= z;
    }
    int c = fflat >> 13, pos = fflat & 8191;
    u32 orig = sorted_orig[(b * 3 + c) * NN + pos];
    const float* row = in + ((size_t)b * NN + orig) * 11;
    const float PI_F = 3.14159265358979323846f;
    float theta = row[6];
    float v = theta / PI_F;
    float fl = floorf(v + 1.0f);
    float lp = theta - fl * PI_F;
    float ang = lp + (1.0f - row[10]) * PI_F;
    float* ob = out + ((size_t)b * MAXN + r) * 7;
    ob[0] = row[0]; ob[1] = row[1]; ob[2] = row[2];
    ob[3] = row[3]; ob[4] = row[4]; ob[5] = row[5]; ob[6] = ang;
    out[NB * MAXN * 7 + b * MAXN + r] = (float)c;
    out[NB * MAXN * 7 + NB * MAXN + b * MAXN + r] = -INFINITY;
  }
}

// ================= standalone fallback (small ws): r2 nms =================
__global__ __launch_bounds__(1024) void nms_kernel(
    const float* __restrict__ in, u32* __restrict__ sorted_orig,
    u64* __restrict__ alive_out, u32* __restrict__ kept_key,
    u32* __restrict__ kept_pos, u32* __restrict__ kept_cnt)
{
  const int g = blockIdx.x;
  const int b = g / NC, c = g % NC;
  const float* __restrict__ base = in + (size_t)b * NN * 11;
  __shared__ u32 keys[NN];
  __shared__ u16 sidx[NN];
  __shared__ float4 keeperBuf[2][64];
  __shared__ int nkBuf[2];
  __shared__ u64 aliveArr[128];
  __shared__ u32 prefix[128];
  const int tid = threadIdx.x;
  const int w = tid >> 6, lane = tid & 63;

  for (int p = tid; p < NN; p += 1024) {
    float sc = base[p * 11 + 7 + c];
    float s = (sc > 0.1f) ? sc : -INFINITY;
    keys[p] = sort_key(s);
    sidx[p] = (u16)p;
  }
  __syncthreads();
  for (int k = 2; k <= NN; k <<= 1) {
    for (int j = k >> 1; j > 0; j >>= 1) {
      for (int t = tid; t < NN / 2; t += 1024) {
        int i = (t << 1) - (t & (j - 1));
        int q = i | j;
        u32 ka = keys[i], kb = keys[q];
        u16 ia = sidx[i], ib = sidx[q];
        bool gt = (ka > kb) || (ka == kb && ia > ib);
        bool up = ((i & k) == 0);
        if (gt == up) { keys[i] = kb; keys[q] = ka; sidx[i] = ib; sidx[q] = ia; }
      }
      __syncthreads();
    }
  }
  float bx1[8], by1[8], bx2[8], by2[8], barea[8];
  u64 alive[8];
#pragma unroll
  for (int k = 0; k < 8; ++k) {
    int p = k * 1024 + tid;
    u32 key = keys[p];
    int orig = sidx[p];
    sorted_orig[g * NN + p] = (u32)orig;
    const float* r = base + orig * 11;
    float x = r[0], y = r[1], l = r[3], wd = r[4];
    float hx = l * 0.5f, hy = wd * 0.5f;
    bx1[k] = x - hx; by1[k] = y - hy; bx2[k] = x + hx; by2[k] = y + hy;
    barea[k] = (bx2[k] - bx1[k]) * (by2[k] - by1[k]);
    alive[k] = __ballot(key != 0xFF800000u);
  }
  for (int cc = 0; cc < 128; ++cc) {
    __syncthreads();
    int nk_prev = (cc > 0) ? nkBuf[(cc - 1) & 1] : 0;
    if (nk_prev > 0) {
      const int par = (cc - 1) & 1;
      for (int j = 0; j < nk_prev; ++j) {
        float4 K = keeperBuf[par][j];
        float ka = (K.z - K.x) * (K.w - K.y);
#pragma unroll
        for (int k = 0; k < 8; ++k) {
          if ((k * 16 + w) < cc) continue;
          if (alive[k] == 0ull) continue;
          float iw = fminf(bx2[k], K.z) - fmaxf(bx1[k], K.x);
          float ih = fminf(by2[k], K.w) - fmaxf(by1[k], K.y);
          iw = fmaxf(iw, 0.0f); ih = fmaxf(ih, 0.0f);
          float inter = iw * ih;
          float denom = (barea[k] + ka) - inter + 1e-8f;
          float t = 0.25f * denom;
          u64 sup = __ballot(inter > t);
          u64 wnd = __ballot(inter > t && inter <= t * NMS_EPS);
          if (wnd) {
            bool bb = inter > t;
            if (bb && inter <= t * NMS_EPS) bb = (inter / denom) > 0.25f;
            sup = __ballot(bb);
          }
          alive[k] &= ~sup;
        }
      }
    }
    if (w == (cc & 15)) {
      float mx1 = 0.f, my1 = 0.f, mx2 = 0.f, my2 = 0.f, ma = 0.f;
      u64 m = 0ull;
#pragma unroll
      for (int k = 0; k < 8; ++k) if (k == (cc >> 4)) {
        mx1 = bx1[k]; my1 = by1[k]; mx2 = bx2[k]; my2 = by2[k]; ma = barea[k];
        m = alive[k];
      }
      u64 keepm = 0ull;
      int nk = 0;
      while (m) {
        int bp = __ffsll(m) - 1;
        keepm |= 1ull << bp;
        m &= ~(1ull << bp);
        float kx1 = __shfl(mx1, bp), ky1 = __shfl(my1, bp);
        float kx2 = __shfl(mx2, bp), ky2 = __shfl(my2, bp);
        float ka = (kx2 - kx1) * (ky2 - ky1);
        float iw = fminf(mx2, kx2) - fmaxf(mx1, kx1);
        float ih = fminf(my2, ky2) - fmaxf(my1, ky1);
        iw = fmaxf(iw, 0.0f); ih = fmaxf(ih, 0.0f);
        float inter = iw * ih;
        float denom = (ma + ka) - inter + 1e-8f;
        float t = 0.25f * denom;
        u64 sup = __ballot(inter > t);
        u64 wnd = __ballot(inter > t && inter <= t * NMS_EPS);
        if (wnd) {
          bool bb = inter > t;
          if (bb && inter <= t * NMS_EPS) bb = (inter / denom) > 0.25f;
          sup = __ballot(bb);
        }
        m &= ~sup;
        if (lane == bp) keeperBuf[cc & 1][nk] = make_float4(mx1, my1, mx2, my2);
        nk++;
      }
#pragma unroll
      for (int k = 0; k < 8; ++k) if (k == (cc >> 4)) alive[k] = keepm;
      if (lane == 0) nkBuf[cc & 1] = nk;
    }
  }
  __syncthreads();
  if (lane == 0) {
#pragma unroll
    for (int k = 0; k < 8; ++k) aliveArr[k * 16 + w] = alive[k];
  }
  __syncthreads();
  if (tid == 0) {
    u32 acc = 0;
    for (int i = 0; i < 128; ++i) { prefix[i] = acc; acc += (u32)__popcll(aliveArr[i]); }
    kept_cnt[g] = acc;
  }
  __syncthreads();
  for (int i = tid; i < 128; i += 1024) alive_out[g * 128 + i] = aliveArr[i];
#pragma unroll
  for (int k = 0; k < 8; ++k) {
    int word = k * 16 + w;
    u64 a = alive[k];
    if ((a >> lane) & 1ull) {
      u32 rank = prefix[word] + (u32)__popcll(a & ((1ull << lane) - 1ull));
      if (rank < KEEP_CAP) {
        int p = k * 1024 + tid;
        kept_key[g * KEEP_CAP + rank] = keys[p];
        kept_pos[g * KEEP_CAP + rank] = (u32)p;
      }
    }
  }
}

extern "C" void kernel_launch(void* const* d_in, const int* in_sizes, int n_in,
                              void* d_out, int out_size, void* d_ws, size_t ws_size,
                              hipStream_t stream) {
  const float* in = (const float*)d_in[0];
  float* out = (float*)d_out;
  char* ws = (char*)d_ws;

  if (ws_size >= (size_t)WS_NEED) {
    u32* so = (u32*)(ws + NSO);
    u32* skey = (u32*)(ws + NSKEY);
    float4* sb4 = (float4*)(ws + NSB4);
    float* sar = (float*)(ws + NSAR);
    u64* valid = (u64*)(ws + NVAL);
    u64* alive = (u64*)(ws + NALV);
    u32* kkey = (u32*)(ws + NKKEY);
    u32* kpos = (u32*)(ws + NKPOS);
    u32* kcnt = (u32*)(ws + NKCNT);
    u32* flags = (u32*)(ws + NFLG);
    u64* pmat = (u64*)(ws + PMAT);
    u64* kk = (u64*)(ws + PMAT);        // alias: dead before build_prefix runs

    sortL_kernel<<<dim3(48), dim3(256), 0, stream>>>(in, kk);
    merge_kernel<<<dim3(NG), dim3(1024), 0, stream>>>(
        in, kk, so, skey, sb4, sar, valid);
    build_prefix_kernel<<<dim3(PB_BLOCKS), dim3(PB_TPB), 0, stream>>>(
        sb4, sar, pmat);
    scan_nms_kernel<<<dim3(NG), dim3(1024), 0, stream>>>(
        pmat, valid, skey, in, so, alive, kkey, kpos, kcnt, flags);
    topk_kernel<<<dim3(NB), dim3(512), 0, stream>>>(
        in, so, alive, kkey, kpos, kcnt, out);
  } else {
    u32* sorted_orig = (u32*)(ws + WS_SORTED_ORIG);
    u64* alive = (u64*)(ws + WS_ALIVE);
    u32* kept_key = (u32*)(ws + WS_KEPT_KEY);
    u32* kept_pos = (u32*)(ws + WS_KEPT_POS);
    u32* kept_cnt = (u32*)(ws + WS_KEPT_CNT);
    nms_kernel<<<dim3(NG), dim3(1024), 0, stream>>>(
        in, sorted_orig, alive, kept_key, kept_pos, kept_cnt);
    topk_kernel<<<dim3(NB), dim3(512), 0, stream>>>(
        in, sorted_orig, alive, kept_key, kept_pos, kept_cnt, out);
  }
}

// Round 22
// 89.918 us; speedup vs baseline: 2.1974x; 1.0896x over previous
//
#include <hip/hip_runtime.h>
#include <stdint.h>

#pragma clang fp contract(off)

#define NB 4
#define NN 8192
#define NC 3
#define NG 12
#define MAXN 500
#define KEEP_CAP 512

typedef unsigned long long u64;
typedef uint32_t u32;
typedef uint16_t u16;

// ---------- ws layout (bytes) ----------
#define NSO   0u
#define NSKEY 393216u
#define NSB4  786432u
#define NSAR  2359296u
#define NVAL  2752512u
#define NALV  2764800u
#define NKKEY 2777088u
#define NKPOS 2801664u
#define NKCNT 2826240u
#define NFLG  2826304u
#define PMAT  3145728u    // u64 [12][32][2048] prefix matrix, TRANSPOSED (aliased as kk)
#define WS_NEED 9437184u

#define PR_CH   32
#define PR_ROWS 2048
#define PUNITS_PER_G 528
#define PB_TPB 256
#define PB_BLOCKS 1584

// ---------- old-path (fallback) ws layout ----------
#define WS_SORTED_ORIG 0
#define WS_ALIVE       393216
#define WS_KEPT_KEY    405504
#define WS_KEPT_POS    430080
#define WS_KEPT_CNT    454656
#define NMS_EPS 1.0000004f

__device__ __forceinline__ u32 sort_key(float s) {
  u32 b = __float_as_uint(s);
  u32 o = (b & 0x80000000u) ? ~b : (b | 0x80000000u);
  return ~o;   // ascending key == descending float; -inf -> 0xFF800000
}

#define PHYS(i) ((i) + ((i) >> 3))
#define CEX(A, B, UP) \
  { if ((x[A] > x[B]) == (UP)) { u64 tt = x[A]; x[A] = x[B]; x[B] = tt; } }

// ========== sort stage 1: per-2048-segment ASCENDING bitonic sort ==========
// 512 threads: LDS stages do 2 iters (was 4); register passes keep tid<256.
__global__ __launch_bounds__(512) void sortL_kernel(
    const float* __restrict__ in, u64* __restrict__ kk)
{
  const int g = blockIdx.x >> 2, seg = blockIdx.x & 3;
  const int b = g / NC, c = g % NC;
  const float* __restrict__ base = in + (size_t)b * NN * 11;
  __shared__ u64 sk[2304];             // PHYS(2047)+1, 18 KiB
  const int tid = threadIdx.x;
  const int gbase = seg << 11;

  for (int i = tid; i < 2048; i += 512) {
    int p = gbase + i;
    float sc = base[p * 11 + 7 + c];
    float s = (sc > 0.1f) ? sc : -INFINITY;
    sk[PHYS(i)] = ((u64)sort_key(s) << 16) | (u32)p;
  }
  __syncthreads();
  if (tid < 256) {
    const int pb = 9 * tid;
    u64 x[8];
#pragma unroll
    for (int a = 0; a < 8; ++a) x[a] = sk[pb + a];
    const bool u8 = ((((tid << 3)) & 8) == 0);   // LOCAL index direction
    CEX(0, 1, true); CEX(2, 3, false); CEX(4, 5, true); CEX(6, 7, false);
    CEX(0, 2, true); CEX(1, 3, true); CEX(4, 6, false); CEX(5, 7, false);
    CEX(0, 1, true); CEX(2, 3, true); CEX(4, 5, false); CEX(6, 7, false);
    CEX(0, 4, u8); CEX(1, 5, u8); CEX(2, 6, u8); CEX(3, 7, u8);
    CEX(0, 2, u8); CEX(1, 3, u8); CEX(4, 6, u8); CEX(5, 7, u8);
    CEX(0, 1, u8); CEX(2, 3, u8); CEX(4, 5, u8); CEX(6, 7, u8);
#pragma unroll
    for (int a = 0; a < 8; ++a) sk[pb + a] = x[a];
  }
  __syncthreads();
  for (int k = 16; k <= 2048; k <<= 1) {
    for (int j = k >> 1; j >= 8; j >>= 1) {
      for (int t = tid; t < 1024; t += 512) {
        int i = (t << 1) - (t & (j - 1));
        int q = i | j;
        int pi = PHYS(i), pq = PHYS(q);
        u64 ka = sk[pi], kb = sk[pq];
        bool up = ((i & k) == 0);                // LOCAL index direction
        if ((ka > kb) == up) { sk[pi] = kb; sk[pq] = ka; }
      }
      __syncthreads();
    }
    if (tid < 256) {
      const int lb = tid << 3;
      const bool up = ((lb & k) == 0);
      const int pb = 9 * tid;
      u64 x[8];
#pragma unroll
      for (int a = 0; a < 8; ++a) x[a] = sk[pb + a];
      CEX(0, 4, up); CEX(1, 5, up); CEX(2, 6, up); CEX(3, 7, up);
      CEX(0, 2, up); CEX(1, 3, up); CEX(4, 6, up); CEX(5, 7, up);
      CEX(0, 1, up); CEX(2, 3, up); CEX(4, 5, up); CEX(6, 7, up);
#pragma unroll
      for (int a = 0; a < 8; ++a) sk[pb + a] = x[a];
    }
    __syncthreads();
  }
  for (int i = tid; i < 2048; i += 512)
    kk[(size_t)g * NN + gbase + i] = sk[PHYS(i)];
}

// ========== merge: exact global top-2048; searches run in LDS ==============
__global__ __launch_bounds__(1024) void merge_kernel(
    const float* __restrict__ in, const u64* __restrict__ kk,
    u32* __restrict__ so, u32* __restrict__ skey, float4* __restrict__ sb4,
    float* __restrict__ sar, u64* __restrict__ valid)
{
  const int g = blockIdx.x;
  const int b = g / NC;
  const int tid = threadIdx.x;
  __shared__ u64 seg[NN];              // 64 KiB
  __shared__ u64 outk[PR_ROWS];        // 16 KiB
  const u64* __restrict__ ks = kk + (size_t)g * NN;

  for (int e = tid; e < NN; e += 1024) seg[e] = ks[e];
  __syncthreads();

  for (int e = tid; e < NN; e += 1024) {
    const int sg = e >> 11, idx = e & 2047;
    const u64 k = seg[e];
    int rank = idx;
#pragma unroll
    for (int os = 0; os < 4; ++os) {
      if (os == sg) continue;
      const u64* __restrict__ arr = seg + (os << 11);
      int pos = 0;
#pragma unroll
      for (int st = 1024; st > 0; st >>= 1) {
        int np = pos + st;
        if (np <= 2048 && arr[np - 1] < k) pos = np;
      }
      rank += pos;
    }
    if (rank < PR_ROWS) outk[rank] = k;
  }
  __syncthreads();

  const float* __restrict__ base = in + (size_t)b * NN * 11;
  const int lane = tid & 63;
#pragma unroll
  for (int it = 0; it < PR_ROWS / 1024; ++it) {
    int i = it * 1024 + tid;
    u64 kv = outk[i];
    int orig = (int)(kv & 0xFFFFu);
    u32 key32 = (u32)(kv >> 16);
    so[(size_t)g * NN + i] = (u32)orig;
    skey[(size_t)g * NN + i] = key32;
    const float* r = base + orig * 11;
    float x = r[0], y = r[1], l = r[3], wd = r[4];
    float hx = l * 0.5f, hy = wd * 0.5f;
    float x1 = x - hx, y1 = y - hy, x2 = x + hx, y2 = y + hy;
    sb4[(size_t)g * NN + i] = make_float4(x1, y1, x2, y2);
    sar[(size_t)g * NN + i] = (x2 - x1) * (y2 - y1);
    u64 bal = __ballot(key32 != 0xFF800000u);
    if (lane == 0) valid[g * 128 + (i >> 6)] = bal;
  }
}

// ================= prefix build: rows 0..2047 x words 0..31 (upper tri) ====
__global__ __launch_bounds__(PB_TPB) void build_prefix_kernel(
    const float4* __restrict__ sb4, const float* __restrict__ sar,
    u64* __restrict__ pmat)
{
  const int wib = __builtin_amdgcn_readfirstlane((int)(threadIdx.x >> 6));
  const int lane = threadIdx.x & 63;
  const int W = blockIdx.x * (PB_TPB / 64) + wib;
  if (W >= NG * PUNITS_PER_G) return;
  const int g = W / PUNITS_PER_G;
  int r = W - g * PUNITS_PER_G;
  int rb = 0, cum = 0;
  while (r >= cum + (PR_CH - rb)) { cum += PR_CH - rb; ++rb; }
  const int jw = rb + (r - cum);
  const double CMULT = 0.25 * (1.0 + 0x1p-24);   // exact in double

  const int col = jw * 64 + lane;
  const float4 J = sb4[(size_t)g * NN + col];
  const float jar = sar[(size_t)g * NN + col];
  const float4* __restrict__ Ib = sb4 + (size_t)g * NN + rb * 64;
  const float* __restrict__ Ia = sar + (size_t)g * NN + rb * 64;

  u32 accLo = 0, accHi = 0;
  for (int rr = 0; rr < 64; ++rr) {
    const float4 I = Ib[rr];            // uniform -> s_load
    const float iar = Ia[rr];
    const bool sel = (lane == rr);
    float iw = fminf(I.z, J.z) - fmaxf(I.x, J.x);
    float ih = fminf(I.w, J.w) - fmaxf(I.y, J.y);
    iw = fmaxf(iw, 0.0f); ih = fmaxf(ih, 0.0f);
    float inter = iw * ih;
    float denom = ((iar + jar) - inter) + 1e-8f;
    u64 cand = __ballot((double)inter > CMULT * (double)denom);
    accLo = sel ? (u32)(cand & 0xffffffffu) : accLo;
    accHi = sel ? (u32)(cand >> 32) : accHi;
  }
  pmat[((size_t)(g * PR_CH + jw)) * PR_ROWS + rb * 64 + lane] =
      ((u64)accHi << 32) | accLo;
}

// ======= prefix scan (fixpoint + early exit) + INLINE gated full NMS =======
__global__ __launch_bounds__(1024) void scan_nms_kernel(
    const u64* __restrict__ pmat, const u64* __restrict__ valid,
    const u32* __restrict__ skey, const float* __restrict__ in,
    u32* __restrict__ so, u64* __restrict__ alive_out,
    u32* __restrict__ kept_key, u32* __restrict__ kept_pos,
    u32* __restrict__ kept_cnt, u32* __restrict__ flags)
{
  const int g = blockIdx.x;
  const int tid = threadIdx.x;
  const int wv = tid >> 6, lane = tid & 63;
  const int wl = tid & 127, grp = tid >> 7;
  __shared__ u64 remv[PR_CH];
  __shared__ u64 keepw[PR_CH];
  __shared__ u64 keepS;
  __shared__ u32 prefixL[PR_CH];
  __shared__ u32 cntS;
  __shared__ int stopS;
  // NMS-path LDS (used only when flag==0)
  __shared__ u32 keys[NN];             // 32 KiB
  __shared__ u16 sidx[NN];             // 16 KiB
  __shared__ float4 keeperBuf[2][64];
  __shared__ int nkBuf[2];
  __shared__ u64 aliveArr[128];
  __shared__ u32 prefixN[128];

  if (tid < PR_CH) { remv[tid] = ~valid[g * 128 + tid]; keepw[tid] = 0; }
  if (tid == 0) { cntS = 0; stopS = 0; }
  __syncthreads();

  const u64* __restrict__ pm = pmat + (size_t)g * PR_CH * PR_ROWS;
  u64 rwDiag = 0, rwDiagNext = 0;
  if (wv == 0) rwDiag = pm[lane];
  const u64 maskgt = (lane == 63) ? 0ull : (~0ull << (lane + 1));

  for (int cc = 0; cc < PR_CH; ++cc) {
    const int w = cc + 1 + wl;
    const bool act = (w < PR_CH);
    u64 rw[8];
    if (act) {
#pragma unroll
      for (int k = 0; k < 8; ++k)
        rw[k] = pm[(size_t)w * PR_ROWS + cc * 64 + grp * 8 + k];
    }
    if (wv == 0) {
      const u64 alive0 = ~remv[cc];
      u64 K = alive0;
      for (int it = 0; it < 64; ++it) {
        u64 contrib = ((K >> lane) & 1ull) ? (rwDiag & maskgt) : 0ull;
#pragma unroll
        for (int off = 32; off > 0; off >>= 1)
          contrib |= (u64)__shfl_xor((long long)contrib, off);
        u64 Knew = alive0 & ~contrib;
        if (Knew == K) break;
        K = Knew;
      }
      if (lane == 0) {
        keepw[cc] = K; keepS = K;
        cntS += (u32)__popcll(K);
        if (cntS >= KEEP_CAP) stopS = 1;
      }
      if (cc + 1 < PR_CH)
        rwDiagNext = pm[(size_t)(cc + 1) * PR_ROWS + (cc + 1) * 64 + lane];
    }
    __syncthreads();
    if (stopS) break;
    if (act) {
      const u32 kmg = (u32)((keepS >> (grp * 8)) & 0xffu);
      u64 acc = 0;
#pragma unroll
      for (int k = 0; k < 8; ++k)
        if ((kmg >> k) & 1u) acc |= rw[k];
      if (acc) atomicOr(&remv[w], acc);
    }
    if (wv == 0) rwDiag = rwDiagNext;
    __syncthreads();
  }
  __syncthreads();

  if (tid == 0) {
    u32 acc = 0;
    for (int i = 0; i < PR_CH; ++i) { prefixL[i] = acc; acc += (u32)__popcll(keepw[i]); }
    cntS = acc;
    u32 ok = (acc >= KEEP_CAP) ? 1u : 0u;
    flags[g] = ok;
    if (ok) kept_cnt[g] = KEEP_CAP;
  }
  __syncthreads();
  if (cntS >= KEEP_CAP) {
    for (int p = tid; p < PR_ROWS; p += 1024) {
      int wd = p >> 6;
      u64 kw = keepw[wd];
      if ((kw >> (p & 63)) & 1ull) {
        u32 rank = prefixL[wd] + (u32)__popcll(kw & ((1ull << (p & 63)) - 1ull));
        if (rank < KEEP_CAP) {
          kept_key[g * KEEP_CAP + rank] = skey[g * NN + p];
          kept_pos[g * KEEP_CAP + rank] = (u32)p;
        }
      }
    }
    return;
  }

  // ---------- inline gated monolithic NMS (flag==0 only; ~never) ----------
  {
    const int b = g / NC, c = g % NC;
    const float* __restrict__ base = in + (size_t)b * NN * 11;
    const int w = tid >> 6;

    for (int p = tid; p < NN; p += 1024) {
      float sc = base[p * 11 + 7 + c];
      float s = (sc > 0.1f) ? sc : -INFINITY;
      keys[p] = sort_key(s);
      sidx[p] = (u16)p;
    }
    __syncthreads();
    for (int k = 2; k <= NN; k <<= 1) {
      for (int j = k >> 1; j > 0; j >>= 1) {
        for (int t = tid; t < NN / 2; t += 1024) {
          int i = (t << 1) - (t & (j - 1));
          int q = i | j;
          u32 ka = keys[i], kb = keys[q];
          u16 ia = sidx[i], ib = sidx[q];
          bool gt = (ka > kb) || (ka == kb && ia > ib);
          bool up = ((i & k) == 0);
          if (gt == up) { keys[i] = kb; keys[q] = ka; sidx[i] = ib; sidx[q] = ia; }
        }
        __syncthreads();
      }
    }
    float bx1[8], by1[8], bx2[8], by2[8], barea[8];
    u64 alv[8];
#pragma unroll
    for (int k = 0; k < 8; ++k) {
      int p = k * 1024 + tid;
      u32 key = keys[p];
      int orig = sidx[p];
      so[(size_t)g * NN + p] = (u32)orig;
      const float* r = base + orig * 11;
      float x = r[0], y = r[1], l = r[3], wd = r[4];
      float hx = l * 0.5f, hy = wd * 0.5f;
      bx1[k] = x - hx; by1[k] = y - hy; bx2[k] = x + hx; by2[k] = y + hy;
      barea[k] = (bx2[k] - bx1[k]) * (by2[k] - by1[k]);
      alv[k] = __ballot(key != 0xFF800000u);
    }
    for (int cc = 0; cc < 128; ++cc) {
      __syncthreads();
      int nk_prev = (cc > 0) ? nkBuf[(cc - 1) & 1] : 0;
      if (nk_prev > 0) {
        const int par = (cc - 1) & 1;
        for (int j = 0; j < nk_prev; ++j) {
          float4 K = keeperBuf[par][j];
          float ka = (K.z - K.x) * (K.w - K.y);
#pragma unroll
          for (int k = 0; k < 8; ++k) {
            if ((k * 16 + w) < cc) continue;
            if (alv[k] == 0ull) continue;
            float iw = fminf(bx2[k], K.z) - fmaxf(bx1[k], K.x);
            float ih = fminf(by2[k], K.w) - fmaxf(by1[k], K.y);
            iw = fmaxf(iw, 0.0f); ih = fmaxf(ih, 0.0f);
            float inter = iw * ih;
            float denom = (barea[k] + ka) - inter + 1e-8f;
            float t = 0.25f * denom;
            u64 sup = __ballot(inter > t);
            u64 wnd = __ballot(inter > t && inter <= t * NMS_EPS);
            if (wnd) {
              bool bb = inter > t;
              if (bb && inter <= t * NMS_EPS) bb = (inter / denom) > 0.25f;
              sup = __ballot(bb);
            }
            alv[k] &= ~sup;
          }
        }
      }
      if (w == (cc & 15)) {
        float mx1 = 0.f, my1 = 0.f, mx2 = 0.f, my2 = 0.f, ma = 0.f;
        u64 m = 0ull;
#pragma unroll
        for (int k = 0; k < 8; ++k) if (k == (cc >> 4)) {
          mx1 = bx1[k]; my1 = by1[k]; mx2 = bx2[k]; my2 = by2[k]; ma = barea[k];
          m = alv[k];
        }
        u64 keepm = 0ull;
        int nk = 0;
        while (m) {
          int bp = __ffsll(m) - 1;
          keepm |= 1ull << bp;
          m &= ~(1ull << bp);
          float kx1 = __shfl(mx1, bp), ky1 = __shfl(my1, bp);
          float kx2 = __shfl(mx2, bp), ky2 = __shfl(my2, bp);
          float ka = (kx2 - kx1) * (ky2 - ky1);
          float iw = fminf(mx2, kx2) - fmaxf(mx1, kx1);
          float ih = fminf(my2, ky2) - fmaxf(my1, ky1);
          iw = fmaxf(iw, 0.0f); ih = fmaxf(ih, 0.0f);
          float inter = iw * ih;
          float denom = (ma + ka) - inter + 1e-8f;
          float t = 0.25f * denom;
          u64 sup = __ballot(inter > t);
          u64 wnd = __ballot(inter > t && inter <= t * NMS_EPS);
          if (wnd) {
            bool bb = inter > t;
            if (bb && inter <= t * NMS_EPS) bb = (inter / denom) > 0.25f;
            sup = __ballot(bb);
          }
          m &= ~sup;
          if (lane == bp) keeperBuf[cc & 1][nk] = make_float4(mx1, my1, mx2, my2);
          nk++;
        }
#pragma unroll
        for (int k = 0; k < 8; ++k) if (k == (cc >> 4)) alv[k] = keepm;
        if (lane == 0) nkBuf[cc & 1] = nk;
      }
    }
    __syncthreads();
    if (lane == 0) {
#pragma unroll
      for (int k = 0; k < 8; ++k) aliveArr[k * 16 + w] = alv[k];
    }
    __syncthreads();
    if (tid == 0) {
      u32 acc = 0;
      for (int i = 0; i < 128; ++i) { prefixN[i] = acc; acc += (u32)__popcll(aliveArr[i]); }
      kept_cnt[g] = acc;
    }
    __syncthreads();
    for (int i = tid; i < 128; i += 1024) alive_out[g * 128 + i] = aliveArr[i];
#pragma unroll
    for (int k = 0; k < 8; ++k) {
      int word = k * 16 + w;
      u64 a = alv[k];
      if ((a >> lane) & 1ull) {
        u32 rank = prefixN[word] + (u32)__popcll(a & ((1ull << lane) - 1ull));
        if (rank < KEEP_CAP) {
          int p = k * 1024 + tid;
          kept_key[g * KEEP_CAP + rank] = keys[p];
          kept_pos[g * KEEP_CAP + rank] = (u32)p;
        }
      }
    }
  }
}

// ============ top-k via 3-way sorted-list merge (no bitonic) ===============
__global__ __launch_bounds__(512) void topk_kernel(
    const float* __restrict__ in, const u32* __restrict__ sorted_orig,
    const u64* __restrict__ alive_ws, const u32* __restrict__ kept_key,
    const u32* __restrict__ kept_pos, const u32* __restrict__ kept_cnt,
    float* __restrict__ out)
{
  const int b = blockIdx.x;
  const int tid = threadIdx.x;
  __shared__ u64 arr[NC][KEEP_CAP];
  __shared__ int sT[3], sL[3];
  if (tid < 3) {
    int K = (int)kept_cnt[b * 3 + tid];
    sT[tid] = K;
    sL[tid] = min(K, KEEP_CAP);
  }
  __syncthreads();
  const int navail = sL[0] + sL[1] + sL[2];
  const int Ttot = sT[0] + sT[1] + sT[2];

  for (int s = tid; s < NC * KEEP_CAP; s += 512) {
    int c = s >> 9, i = s & 511;
    u64 key = ~0ull;
    if (i < sL[c]) {
      int g = b * 3 + c;
      u64 k32 = kept_key[g * KEEP_CAP + i];
      u32 pos = kept_pos[g * KEEP_CAP + i];
      key = (k32 << 15) | (u32)(c * NN + pos);
    }
    arr[c][i] = key;
  }
  __syncthreads();

  for (int s = tid; s < NC * KEEP_CAP; s += 512) {
    int c = s >> 9, i = s & 511;
    if (i >= sL[c]) continue;
    u64 k = arr[c][i];
    int rank = i;
#pragma unroll
    for (int oc = 0; oc < NC; ++oc) {
      if (oc == c) continue;
      int lo = 0, hi = sL[oc];
      while (lo < hi) { int mid = (lo + hi) >> 1; if (arr[oc][mid] < k) lo = mid + 1; else hi = mid; }
      rank += lo;
    }
    if (rank < MAXN) {
      u32 flat = (u32)(k & 32767u);
      int cc = (int)(flat >> 13), pos = (int)(flat & 8191);
      u32 k32 = (u32)(k >> 15);
      u32 o = ~k32;
      u32 bits = (o & 0x80000000u) ? (o ^ 0x80000000u) : ~o;
      float sval = __uint_as_float(bits);
      u32 orig = sorted_orig[(b * 3 + cc) * NN + pos];
      const float* row = in + ((size_t)b * NN + orig) * 11;
      const float PI_F = 3.14159265358979323846f;
      float theta = row[6];
      float v = theta / PI_F;
      float fl = floorf(v + 1.0f);
      float lp = theta - fl * PI_F;
      float ang = lp + (1.0f - row[10]) * PI_F;
      float* ob = out + ((size_t)b * MAXN + rank) * 7;
      ob[0] = row[0]; ob[1] = row[1]; ob[2] = row[2];
      ob[3] = row[3]; ob[4] = row[4]; ob[5] = row[5]; ob[6] = ang;
      out[NB * MAXN * 7 + b * MAXN + rank] = (float)cc;
      out[NB * MAXN * 7 + NB * MAXN + b * MAXN + rank] = sval;
    }
  }

  for (int r = navail + tid; r < MAXN; r += 512) {
    int need = r - Ttot;
    int fflat = 0;
    for (int wd = 0; wd < 384; ++wd) {
      u64 a = alive_ws[b * 384 + wd];
      int z = 64 - __popcll(a);
      if (need < z) {
        u64 na = ~a;
        for (int it = 0; it < need; ++it) na &= na - 1ull;
        fflat = wd * 64 + (__ffsll(na) - 1);
        break;
      }
      need -= z;
    }
    int c = fflat >> 13, pos = fflat & 8191;
    u32 orig = sorted_orig[(b * 3 + c) * NN + pos];
    const float* row = in + ((size_t)b * NN + orig) * 11;
    const float PI_F = 3.14159265358979323846f;
    float theta = row[6];
    float v = theta / PI_F;
    float fl = floorf(v + 1.0f);
    float lp = theta - fl * PI_F;
    float ang = lp + (1.0f - row[10]) * PI_F;
    float* ob = out + ((size_t)b * MAXN + r) * 7;
    ob[0] = row[0]; ob[1] = row[1]; ob[2] = row[2];
    ob[3] = row[3]; ob[4] = row[4]; ob[5] = row[5]; ob[6] = ang;
    out[NB * MAXN * 7 + b * MAXN + r] = (float)c;
    out[NB * MAXN * 7 + NB * MAXN + b * MAXN + r] = -INFINITY;
  }
}

// ================= standalone fallback (small ws): r2 nms =================
__global__ __launch_bounds__(1024) void nms_kernel(
    const float* __restrict__ in, u32* __restrict__ sorted_orig,
    u64* __restrict__ alive_out, u32* __restrict__ kept_key,
    u32* __restrict__ kept_pos, u32* __restrict__ kept_cnt)
{
  const int g = blockIdx.x;
  const int b = g / NC, c = g % NC;
  const float* __restrict__ base = in + (size_t)b * NN * 11;
  __shared__ u32 keys[NN];
  __shared__ u16 sidx[NN];
  __shared__ float4 keeperBuf[2][64];
  __shared__ int nkBuf[2];
  __shared__ u64 aliveArr[128];
  __shared__ u32 prefix[128];
  const int tid = threadIdx.x;
  const int w = tid >> 6, lane = tid & 63;

  for (int p = tid; p < NN; p += 1024) {
    float sc = base[p * 11 + 7 + c];
    float s = (sc > 0.1f) ? sc : -INFINITY;
    keys[p] = sort_key(s);
    sidx[p] = (u16)p;
  }
  __syncthreads();
  for (int k = 2; k <= NN; k <<= 1) {
    for (int j = k >> 1; j > 0; j >>= 1) {
      for (int t = tid; t < NN / 2; t += 1024) {
        int i = (t << 1) - (t & (j - 1));
        int q = i | j;
        u32 ka = keys[i], kb = keys[q];
        u16 ia = sidx[i], ib = sidx[q];
        bool gt = (ka > kb) || (ka == kb && ia > ib);
        bool up = ((i & k) == 0);
        if (gt == up) { keys[i] = kb; keys[q] = ka; sidx[i] = ib; sidx[q] = ia; }
      }
      __syncthreads();
    }
  }
  float bx1[8], by1[8], bx2[8], by2[8], barea[8];
  u64 alive[8];
#pragma unroll
  for (int k = 0; k < 8; ++k) {
    int p = k * 1024 + tid;
    u32 key = keys[p];
    int orig = sidx[p];
    sorted_orig[g * NN + p] = (u32)orig;
    const float* r = base + orig * 11;
    float x = r[0], y = r[1], l = r[3], wd = r[4];
    float hx = l * 0.5f, hy = wd * 0.5f;
    bx1[k] = x - hx; by1[k] = y - hy; bx2[k] = x + hx; by2[k] = y + hy;
    barea[k] = (bx2[k] - bx1[k]) * (by2[k] - by1[k]);
    alive[k] = __ballot(key != 0xFF800000u);
  }
  for (int cc = 0; cc < 128; ++cc) {
    __syncthreads();
    int nk_prev = (cc > 0) ? nkBuf[(cc - 1) & 1] : 0;
    if (nk_prev > 0) {
      const int par = (cc - 1) & 1;
      for (int j = 0; j < nk_prev; ++j) {
        float4 K = keeperBuf[par][j];
        float ka = (K.z - K.x) * (K.w - K.y);
#pragma unroll
        for (int k = 0; k < 8; ++k) {
          if ((k * 16 + w) < cc) continue;
          if (alive[k] == 0ull) continue;
          float iw = fminf(bx2[k], K.z) - fmaxf(bx1[k], K.x);
          float ih = fminf(by2[k], K.w) - fmaxf(by1[k], K.y);
          iw = fmaxf(iw, 0.0f); ih = fmaxf(ih, 0.0f);
          float inter = iw * ih;
          float denom = (barea[k] + ka) - inter + 1e-8f;
          float t = 0.25f * denom;
          u64 sup = __ballot(inter > t);
          u64 wnd = __ballot(inter > t && inter <= t * NMS_EPS);
          if (wnd) {
            bool bb = inter > t;
            if (bb && inter <= t * NMS_EPS) bb = (inter / denom) > 0.25f;
            sup = __ballot(bb);
          }
          alive[k] &= ~sup;
        }
      }
    }
    if (w == (cc & 15)) {
      float mx1 = 0.f, my1 = 0.f, mx2 = 0.f, my2 = 0.f, ma = 0.f;
      u64 m = 0ull;
#pragma unroll
      for (int k = 0; k < 8; ++k) if (k == (cc >> 4)) {
        mx1 = bx1[k]; my1 = by1[k]; mx2 = bx2[k]; my2 = by2[k]; ma = barea[k];
        m = alive[k];
      }
      u64 keepm = 0ull;
      int nk = 0;
      while (m) {
        int bp = __ffsll(m) - 1;
        keepm |= 1ull << bp;
        m &= ~(1ull << bp);
        float kx1 = __shfl(mx1, bp), ky1 = __shfl(my1, bp);
        float kx2 = __shfl(mx2, bp), ky2 = __shfl(my2, bp);
        float ka = (kx2 - kx1) * (ky2 - ky1);
        float iw = fminf(mx2, kx2) - fmaxf(mx1, kx1);
        float ih = fminf(my2, ky2) - fmaxf(my1, ky1);
        iw = fmaxf(iw, 0.0f); ih = fmaxf(ih, 0.0f);
        float inter = iw * ih;
        float denom = (ma + ka) - inter + 1e-8f;
        float t = 0.25f * denom;
        u64 sup = __ballot(inter > t);
        u64 wnd = __ballot(inter > t && inter <= t * NMS_EPS);
        if (wnd) {
          bool bb = inter > t;
          if (bb && inter <= t * NMS_EPS) bb = (inter / denom) > 0.25f;
          sup = __ballot(bb);
        }
        m &= ~sup;
        if (lane == bp) keeperBuf[cc & 1][nk] = make_float4(mx1, my1, mx2, my2);
        nk++;
      }
#pragma unroll
      for (int k = 0; k < 8; ++k) if (k == (cc >> 4)) alive[k] = keepm;
      if (lane == 0) nkBuf[cc & 1] = nk;
    }
  }
  __syncthreads();
  if (lane == 0) {
#pragma unroll
    for (int k = 0; k < 8; ++k) aliveArr[k * 16 + w] = alive[k];
  }
  __syncthreads();
  if (tid == 0) {
    u32 acc = 0;
    for (int i = 0; i < 128; ++i) { prefix[i] = acc; acc += (u32)__popcll(aliveArr[i]); }
    kept_cnt[g] = acc;
  }
  __syncthreads();
  for (int i = tid; i < 128; i += 1024) alive_out[g * 128 + i] = aliveArr[i];
#pragma unroll
  for (int k = 0; k < 8; ++k) {
    int word = k * 16 + w;
    u64 a = alive[k];
    if ((a >> lane) & 1ull) {
      u32 rank = prefix[word] + (u32)__popcll(a & ((1ull << lane) - 1ull));
      if (rank < KEEP_CAP) {
        int p = k * 1024 + tid;
        kept_key[g * KEEP_CAP + rank] = keys[p];
        kept_pos[g * KEEP_CAP + rank] = (u32)p;
      }
    }
  }
}

extern "C" void kernel_launch(void* const* d_in, const int* in_sizes, int n_in,
                              void* d_out, int out_size, void* d_ws, size_t ws_size,
                              hipStream_t stream) {
  const float* in = (const float*)d_in[0];
  float* out = (float*)d_out;
  char* ws = (char*)d_ws;

  if (ws_size >= (size_t)WS_NEED) {
    u32* so = (u32*)(ws + NSO);
    u32* skey = (u32*)(ws + NSKEY);
    float4* sb4 = (float4*)(ws + NSB4);
    float* sar = (float*)(ws + NSAR);
    u64* valid = (u64*)(ws + NVAL);
    u64* alive = (u64*)(ws + NALV);
    u32* kkey = (u32*)(ws + NKKEY);
    u32* kpos = (u32*)(ws + NKPOS);
    u32* kcnt = (u32*)(ws + NKCNT);
    u32* flags = (u32*)(ws + NFLG);
    u64* pmat = (u64*)(ws + PMAT);
    u64* kk = (u64*)(ws + PMAT);        // alias: dead before build_prefix runs

    sortL_kernel<<<dim3(48), dim3(512), 0, stream>>>(in, kk);
    merge_kernel<<<dim3(NG), dim3(1024), 0, stream>>>(
        in, kk, so, skey, sb4, sar, valid);
    build_prefix_kernel<<<dim3(PB_BLOCKS), dim3(PB_TPB), 0, stream>>>(
        sb4, sar, pmat);
    scan_nms_kernel<<<dim3(NG), dim3(1024), 0, stream>>>(
        pmat, valid, skey, in, so, alive, kkey, kpos, kcnt, flags);
    topk_kernel<<<dim3(NB), dim3(512), 0, stream>>>(
        in, so, alive, kkey, kpos, kcnt, out);
  } else {
    u32* sorted_orig = (u32*)(ws + WS_SORTED_ORIG);
    u64* alive = (u64*)(ws + WS_ALIVE);
    u32* kept_key = (u32*)(ws + WS_KEPT_KEY);
    u32* kept_pos = (u32*)(ws + WS_KEPT_POS);
    u32* kept_cnt = (u32*)(ws + WS_KEPT_CNT);
    nms_kernel<<<dim3(NG), dim3(1024), 0, stream>>>(
        in, sorted_orig, alive, kept_key, kept_pos, kept_cnt);
    topk_kernel<<<dim3(NB), dim3(512), 0, stream>>>(
        in, sorted_orig, alive, kept_key, kept_pos, kept_cnt, out);
  }
}